// Round 18
// baseline (2210.774 us; speedup 1.0000x reference)
//
#include <hip/hip_runtime.h>

#define HID 256

typedef unsigned short u16;
typedef __attribute__((ext_vector_type(8))) short bf16x8;
typedef __attribute__((ext_vector_type(4))) float f32x4;

__device__ __forceinline__ float siluf(float x) { return x / (1.f + __expf(-x)); }
// tanh-approx gelu via sigmoid identity: 0.5x(1+tanh(z)) == x*sigmoid(2z)
__device__ __forceinline__ float geluf(float x) {
    return x / (1.f + __expf(-(1.59576912f * x + 0.07135481f * x * x * x)));
}
__device__ __forceinline__ u16 f2b(float x) {
    unsigned u = __float_as_uint(x);
    unsigned r = u + 0x7FFFu + ((u >> 16) & 1u);
    return (u16)(r >> 16);
}
__device__ __forceinline__ float b2f(u16 h) {
    return __uint_as_float(((unsigned)h) << 16);
}
__device__ __forceinline__ void gload16(const u16* g, u16* l) {
    __builtin_amdgcn_global_load_lds(
        (const __attribute__((address_space(1))) unsigned int*)g,
        (__attribute__((address_space(3))) unsigned int*)l, 16, 0, 0);
}
__device__ __forceinline__ int imin(int a, int b) { return a < b ? a : b; }

union B16x8 { u16 u[8]; uint4 q; };

// ---------------- bf16 MFMA GEMM: C = act(A @ Bt^T + bias) ------------------------------
__global__ __launch_bounds__(256) void gemm_mfma(
    const u16* __restrict__ A, int lda,
    const u16* __restrict__ Bt, int ldb,
    void* __restrict__ Cv, int ldc,
    int M, int N, int K,
    const float* __restrict__ bias, int act, int obf16)
{
    __shared__ u16 lds[8192];

    const int tid  = threadIdx.x;
    const int lane = tid & 63;
    const int wave = tid >> 6;
    const int row0 = blockIdx.y * 64;
    const int col0 = blockIdx.x * 128;
    const int wm   = (wave >> 1) * 32;
    const int wn   = (wave & 1) * 64;

    f32x4 acc[2][4];
#pragma unroll
    for (int i = 0; i < 2; ++i)
#pragma unroll
        for (int j = 0; j < 4; ++j) acc[i][j] = (f32x4)0.0f;

    const int kc = (lane & 3) * 8;
    const int rr  = wave * 16 + (lane >> 2);
    const int rb1 = (wave + 4) * 16 + (lane >> 2);
    const u16* pa  = A + (size_t)imin(row0 + rr, M - 1) * lda + kc;
    const u16* pb0 = Bt + (size_t)(col0 + rr) * ldb + kc;
    const u16* pb1 = Bt + (size_t)(col0 + rb1) * ldb + kc;
    u16* la  = &lds[wave * 512];
    u16* lb0 = &lds[2048 + wave * 512];
    u16* lb1 = &lds[2048 + (wave + 4) * 512];

    const int kb = (lane >> 4) * 8;
    const int fr = lane & 15;

    for (int k0 = 0; k0 < K; k0 += 32) {
        gload16(pa + k0, la);
        gload16(pb0 + k0, lb0);
        gload16(pb1 + k0, lb1);
        __syncthreads();

        bf16x8 af[2], bfm[4];
#pragma unroll
        for (int i = 0; i < 2; ++i)
            af[i] = *(const bf16x8*)&lds[(wm + i * 16 + fr) * 32 + kb];
#pragma unroll
        for (int j = 0; j < 4; ++j)
            bfm[j] = *(const bf16x8*)&lds[2048 + (wn + j * 16 + fr) * 32 + kb];
#pragma unroll
        for (int i = 0; i < 2; ++i)
#pragma unroll
            for (int j = 0; j < 4; ++j)
                acc[i][j] = __builtin_amdgcn_mfma_f32_16x16x32_bf16(af[i], bfm[j], acc[i][j], 0, 0, 0);
        __syncthreads();
    }

    const int qr = (lane >> 4) * 4;
    if (obf16) {
#pragma unroll
        for (int i = 0; i < 2; ++i)
#pragma unroll
            for (int r = 0; r < 4; ++r)
#pragma unroll
                for (int j = 0; j < 4; ++j) {
                    int lcol = wn + j * 16 + fr;
                    int gcol = col0 + lcol;
                    float v = acc[i][j][r];
                    if (bias) v += bias[gcol];
                    if (act == 2) v = geluf(v);
                    else if (act == 1) v = siluf(v);
                    lds[(wm + i * 16 + qr + r) * 128 + lcol] = f2b(v);
                }
        __syncthreads();
        int row = tid >> 2, cc0 = (tid & 3) * 32;
        int grow = row0 + row;
        if (grow < M) {
            uint4* dst = (uint4*)((u16*)Cv + (size_t)grow * ldc + col0 + cc0);
            const uint4* sp = (const uint4*)&lds[row * 128 + cc0];
            dst[0] = sp[0]; dst[1] = sp[1]; dst[2] = sp[2]; dst[3] = sp[3];
        }
    } else {
        float* Cf = (float*)Cv;
#pragma unroll
        for (int i = 0; i < 2; ++i)
#pragma unroll
            for (int r = 0; r < 4; ++r) {
                int grow = row0 + wm + i * 16 + qr + r;
                if (grow >= M) continue;
#pragma unroll
                for (int j = 0; j < 4; ++j) {
                    int gcol = col0 + wn + j * 16 + fr;
                    float v = acc[i][j][r];
                    if (bias) v += bias[gcol];
                    if (act == 2) v = geluf(v);
                    else if (act == 1) v = siluf(v);
                    Cf[(size_t)grow * ldc + gcol] = v;
                }
            }
    }
}

// ------- gemm_e01: fused [gelu(emod@We0)->alpha | emod@We1->e1b] ------------------------
__global__ __launch_bounds__(256) void gemm_e01(
    const u16* __restrict__ A, const u16* __restrict__ Bt,
    u16* __restrict__ e1b, int M,
    const u16* __restrict__ qkv, const int* __restrict__ srcI, const int* __restrict__ tgtI,
    float* __restrict__ alpha)
{
    __shared__ u16 lds[8192];

    const int tid  = threadIdx.x;
    const int lane = tid & 63;
    const int wave = tid >> 6;
    const int row0 = blockIdx.y * 64;
    const int bx   = blockIdx.x;
    const int col0 = bx * 128;
    const int wm   = (wave >> 1) * 32;
    const int wn   = (wave & 1) * 64;

    f32x4 acc[2][4];
#pragma unroll
    for (int i = 0; i < 2; ++i)
#pragma unroll
        for (int j = 0; j < 4; ++j) acc[i][j] = (f32x4)0.0f;

    const int kc = (lane & 3) * 8;
    const int rr  = wave * 16 + (lane >> 2);
    const int rb1 = (wave + 4) * 16 + (lane >> 2);
    const u16* pa  = A + (size_t)imin(row0 + rr, M - 1) * 256 + kc;
    const u16* pb0 = Bt + (size_t)(col0 + rr) * 256 + kc;
    const u16* pb1 = Bt + (size_t)(col0 + rb1) * 256 + kc;
    u16* la  = &lds[wave * 512];
    u16* lb0 = &lds[2048 + wave * 512];
    u16* lb1 = &lds[2048 + (wave + 4) * 512];

    const int kb = (lane >> 4) * 8;
    const int fr = lane & 15;

    for (int k0 = 0; k0 < 256; k0 += 32) {
        gload16(pa + k0, la);
        gload16(pb0 + k0, lb0);
        gload16(pb1 + k0, lb1);
        __syncthreads();

        bf16x8 af[2], bfm[4];
#pragma unroll
        for (int i = 0; i < 2; ++i)
            af[i] = *(const bf16x8*)&lds[(wm + i * 16 + fr) * 32 + kb];
#pragma unroll
        for (int j = 0; j < 4; ++j)
            bfm[j] = *(const bf16x8*)&lds[2048 + (wn + j * 16 + fr) * 32 + kb];
#pragma unroll
        for (int i = 0; i < 2; ++i)
#pragma unroll
            for (int j = 0; j < 4; ++j)
                acc[i][j] = __builtin_amdgcn_mfma_f32_16x16x32_bf16(af[i], bfm[j], acc[i][j], 0, 0, 0);
        __syncthreads();
    }

    const int qr = (lane >> 4) * 4;
    const bool isE0 = (bx < 2);
#pragma unroll
    for (int i = 0; i < 2; ++i)
#pragma unroll
        for (int r = 0; r < 4; ++r)
#pragma unroll
            for (int j = 0; j < 4; ++j) {
                int lcol = wn + j * 16 + fr;
                float v = acc[i][j][r];
                if (isE0) v = geluf(v);
                lds[(wm + i * 16 + qr + r) * 128 + lcol] = f2b(v);
            }
    __syncthreads();
    int row = tid >> 2, cc0 = (tid & 3) * 32;
    int grow = row0 + row;
    if (grow < M) {
        if (isE0) {
            int head = bx * 4 + (tid & 3);
            const u16* qv = qkv + (size_t)srcI[grow] * 768 + head * 32;
            const u16* kv = qkv + (size_t)tgtI[grow] * 768 + 256 + head * 32;
            const u16* gv = &lds[row * 128 + cc0];
            float s = 0.f;
#pragma unroll
            for (int c = 0; c < 32; ++c)
                s += b2f(gv[c]) * b2f(qv[c]) * b2f(kv[c]);
            alpha[(size_t)grow * 8 + head] = s * 0.17677669529663687f;
        } else {
            uint4* dst = (uint4*)(e1b + (size_t)grow * 256 + (col0 - 256) + cc0);
            const uint4* sp = (const uint4*)&lds[row * 128 + cc0];
            dst[0] = sp[0]; dst[1] = sp[1]; dst[2] = sp[2]; dst[3] = sp[3];
        }
    }
}

// ------- gemm_cat: C(bf16) = [A1(fp32,256) | A2(fp32,128)] @ Bt^T + bias ----------------
__global__ __launch_bounds__(256) void gemm_cat(
    const float* __restrict__ A1, const float* __restrict__ A2,
    const u16* __restrict__ Bt,
    u16* __restrict__ C, int M, const float* __restrict__ bias)
{
    __shared__ u16 lds[8192];

    const int tid  = threadIdx.x;
    const int lane = tid & 63;
    const int wave = tid >> 6;
    const int row0 = blockIdx.y * 64;
    const int col0 = blockIdx.x * 128;
    const int wm   = (wave >> 1) * 32;
    const int wn   = (wave & 1) * 64;

    f32x4 acc[2][4];
#pragma unroll
    for (int i = 0; i < 2; ++i)
#pragma unroll
        for (int j = 0; j < 4; ++j) acc[i][j] = (f32x4)0.0f;

    const int kc = (lane & 3) * 8;
    const int rr  = wave * 16 + (lane >> 2);
    const int rb1 = (wave + 4) * 16 + (lane >> 2);
    const int gr  = imin(row0 + rr, M - 1);
    const u16* pb0 = Bt + (size_t)(col0 + rr) * 384 + kc;
    const u16* pb1 = Bt + (size_t)(col0 + rb1) * 384 + kc;
    u16* lb0 = &lds[2048 + wave * 512];
    u16* lb1 = &lds[2048 + (wave + 4) * 512];
    u16* laD = &lds[wave * 512 + (lane & 63) * 8];

    const int kb = (lane >> 4) * 8;
    const int fr = lane & 15;

    for (int k0 = 0; k0 < 384; k0 += 32) {
        int kk = k0 + kc;
        const float* sp = (kk < 256) ? (A1 + (size_t)gr * 256 + kk)
                                     : (A2 + (size_t)gr * 128 + (kk - 256));
        float4 v0 = *(const float4*)sp;
        float4 v1 = *(const float4*)(sp + 4);
        gload16(pb0 + k0, lb0);
        gload16(pb1 + k0, lb1);
        B16x8 t;
        t.u[0] = f2b(v0.x); t.u[1] = f2b(v0.y); t.u[2] = f2b(v0.z); t.u[3] = f2b(v0.w);
        t.u[4] = f2b(v1.x); t.u[5] = f2b(v1.y); t.u[6] = f2b(v1.z); t.u[7] = f2b(v1.w);
        *(uint4*)laD = t.q;
        __syncthreads();

        bf16x8 af[2], bfm[4];
#pragma unroll
        for (int i = 0; i < 2; ++i)
            af[i] = *(const bf16x8*)&lds[(wm + i * 16 + fr) * 32 + kb];
#pragma unroll
        for (int j = 0; j < 4; ++j)
            bfm[j] = *(const bf16x8*)&lds[2048 + (wn + j * 16 + fr) * 32 + kb];
#pragma unroll
        for (int i = 0; i < 2; ++i)
#pragma unroll
            for (int j = 0; j < 4; ++j)
                acc[i][j] = __builtin_amdgcn_mfma_f32_16x16x32_bf16(af[i], bfm[j], acc[i][j], 0, 0, 0);
        __syncthreads();
    }

    const int qr = (lane >> 4) * 4;
#pragma unroll
    for (int i = 0; i < 2; ++i)
#pragma unroll
        for (int r = 0; r < 4; ++r)
#pragma unroll
            for (int j = 0; j < 4; ++j) {
                int lcol = wn + j * 16 + fr;
                float v = acc[i][j][r] + bias[col0 + lcol];
                lds[(wm + i * 16 + qr + r) * 128 + lcol] = f2b(v);
            }
    __syncthreads();
    int row = tid >> 2, cc0 = (tid & 3) * 32;
    int grow = row0 + row;
    if (grow < M) {
        uint4* dst = (uint4*)(C + (size_t)grow * 256 + col0 + cc0);
        const uint4* sp = (const uint4*)&lds[row * 128 + cc0];
        dst[0] = sp[0]; dst[1] = sp[1]; dst[2] = sp[2]; dst[3] = sp[3];
    }
}

// ------- gemm_gsum: C(bf16) = (hat[src]+hat[tgt]) @ Wn2e^T + b_n2e ----------------------
__global__ __launch_bounds__(256) void gemm_gsum(
    const float* __restrict__ hat, const int* __restrict__ srcI, const int* __restrict__ tgtI,
    const u16* __restrict__ Bt,
    u16* __restrict__ C, int M, const float* __restrict__ bias)
{
    __shared__ u16 lds[8192];

    const int tid  = threadIdx.x;
    const int lane = tid & 63;
    const int wave = tid >> 6;
    const int row0 = blockIdx.y * 64;
    const int col0 = blockIdx.x * 128;
    const int wm   = (wave >> 1) * 32;
    const int wn   = (wave & 1) * 64;

    f32x4 acc[2][4];
#pragma unroll
    for (int i = 0; i < 2; ++i)
#pragma unroll
        for (int j = 0; j < 4; ++j) acc[i][j] = (f32x4)0.0f;

    const int kc = (lane & 3) * 8;
    const int rr  = wave * 16 + (lane >> 2);
    const int rb1 = (wave + 4) * 16 + (lane >> 2);
    const int gr  = imin(row0 + rr, M - 1);
    const float* ps = hat + (size_t)srcI[gr] * 256 + kc;
    const float* pt = hat + (size_t)tgtI[gr] * 256 + kc;
    const u16* pb0 = Bt + (size_t)(col0 + rr) * 256 + kc;
    const u16* pb1 = Bt + (size_t)(col0 + rb1) * 256 + kc;
    u16* lb0 = &lds[2048 + wave * 512];
    u16* lb1 = &lds[2048 + (wave + 4) * 512];
    u16* laD = &lds[wave * 512 + (lane & 63) * 8];

    const int kb = (lane >> 4) * 8;
    const int fr = lane & 15;

    for (int k0 = 0; k0 < 256; k0 += 32) {
        float4 a0 = *(const float4*)(ps + k0);
        float4 a1 = *(const float4*)(ps + k0 + 4);
        float4 b0 = *(const float4*)(pt + k0);
        float4 b1 = *(const float4*)(pt + k0 + 4);
        gload16(pb0 + k0, lb0);
        gload16(pb1 + k0, lb1);
        B16x8 t;
        t.u[0] = f2b(a0.x + b0.x); t.u[1] = f2b(a0.y + b0.y);
        t.u[2] = f2b(a0.z + b0.z); t.u[3] = f2b(a0.w + b0.w);
        t.u[4] = f2b(a1.x + b1.x); t.u[5] = f2b(a1.y + b1.y);
        t.u[6] = f2b(a1.z + b1.z); t.u[7] = f2b(a1.w + b1.w);
        *(uint4*)laD = t.q;
        __syncthreads();

        bf16x8 af[2], bfm[4];
#pragma unroll
        for (int i = 0; i < 2; ++i)
            af[i] = *(const bf16x8*)&lds[(wm + i * 16 + fr) * 32 + kb];
#pragma unroll
        for (int j = 0; j < 4; ++j)
            bfm[j] = *(const bf16x8*)&lds[2048 + (wn + j * 16 + fr) * 32 + kb];
#pragma unroll
        for (int i = 0; i < 2; ++i)
#pragma unroll
            for (int j = 0; j < 4; ++j)
                acc[i][j] = __builtin_amdgcn_mfma_f32_16x16x32_bf16(af[i], bfm[j], acc[i][j], 0, 0, 0);
        __syncthreads();
    }

    const int qr = (lane >> 4) * 4;
#pragma unroll
    for (int i = 0; i < 2; ++i)
#pragma unroll
        for (int r = 0; r < 4; ++r)
#pragma unroll
            for (int j = 0; j < 4; ++j) {
                int lcol = wn + j * 16 + fr;
                float v = acc[i][j][r] + bias[col0 + lcol];
                lds[(wm + i * 16 + qr + r) * 128 + lcol] = f2b(v);
            }
    __syncthreads();
    int row = tid >> 2, cc0 = (tid & 3) * 32;
    int grow = row0 + row;
    if (grow < M) {
        uint4* dst = (uint4*)(C + (size_t)grow * 256 + col0 + cc0);
        const uint4* sp = (const uint4*)&lds[row * 128 + cc0];
        dst[0] = sp[0]; dst[1] = sp[1]; dst[2] = sp[2]; dst[3] = sp[3];
    }
}

// ------- gemm_ffn_full: out = [eae +] A + gate*((silu(A@W12a)*(A@W12b)) @ Wout) ---------
// A: M x 256 bf16. W12t: 2048 x 256 (rows 0..1023 a-cols, 1024..2047 b-cols).
// Woutt: 256 x 1024 (rows = out cols). out: M x 256 fp32. gate bf16 (ldg, goff).
// Block: 32 rows x 256 out cols; DFF looped in 8 slices of 128. grid = ceil(M/32).
// Swiglu intermediate lives only in LDS (Ps). 26 KB LDS.
__global__ __launch_bounds__(256) void gemm_ffn_full(
    const u16* __restrict__ A, const u16* __restrict__ W12t, const u16* __restrict__ Woutt,
    const u16* __restrict__ eae, const u16* __restrict__ gate, int ldg, int goff,
    float* __restrict__ out, int M)
{
    __shared__ u16 lds[13312];        // As[32][32]=1024 | Bs 8192 | Ps[32][128]=4096
    u16* As = lds;
    u16* Bs = lds + 1024;
    u16* Ps = lds + 9216;

    const int tid  = threadIdx.x;
    const int lane = tid & 63;
    const int wave = tid >> 6;
    const int row0 = blockIdx.x * 32;

    const int kc   = (lane & 3) * 8;
    const int rstg = lane >> 2;        // 0..15
    const int kb   = (lane >> 4) * 8;
    const int fr   = lane & 15;
    const int qr   = (lane >> 4) * 4;

    f32x4 oacc[2][4];
#pragma unroll
    for (int i = 0; i < 2; ++i)
#pragma unroll
        for (int j = 0; j < 4; ++j) oacc[i][j] = (f32x4)0.0f;

    const int arow = imin(row0 + (wave & 1) * 16 + rstg, M - 1);   // A staging row (waves 0,1)

    for (int js = 0; js < 8; ++js) {
        // ---- phase A: P[32][128] = silu(A @ W12a_js) * (A @ W12b_js), K=256 ----
        f32x4 pa[2][2], pb[2][2];
#pragma unroll
        for (int i = 0; i < 2; ++i)
#pragma unroll
            for (int j = 0; j < 2; ++j) { pa[i][j] = (f32x4)0.0f; pb[i][j] = (f32x4)0.0f; }

        for (int k0 = 0; k0 < 256; k0 += 32) {
            if (wave < 2)
                gload16(A + (size_t)arow * 256 + k0 + kc, As + (wave & 1) * 512);
#pragma unroll
            for (int h = 0; h < 2; ++h) {
                int rB = h * 64 + wave * 16 + rstg;
                gload16(W12t + (size_t)(js * 128 + rB) * 256 + k0 + kc,
                        Bs + (h * 64 + wave * 16) * 32);
                gload16(W12t + (size_t)(1024 + js * 128 + rB) * 256 + k0 + kc,
                        Bs + 4096 + (h * 64 + wave * 16) * 32);
            }
            __syncthreads();

            bf16x8 af[2], b1f[2], b2f_[2];
#pragma unroll
            for (int i = 0; i < 2; ++i)
                af[i] = *(const bf16x8*)&As[(i * 16 + fr) * 32 + kb];
#pragma unroll
            for (int j = 0; j < 2; ++j) {
                b1f[j]  = *(const bf16x8*)&Bs[(wave * 32 + j * 16 + fr) * 32 + kb];
                b2f_[j] = *(const bf16x8*)&Bs[4096 + (wave * 32 + j * 16 + fr) * 32 + kb];
            }
#pragma unroll
            for (int i = 0; i < 2; ++i)
#pragma unroll
                for (int j = 0; j < 2; ++j) {
                    pa[i][j] = __builtin_amdgcn_mfma_f32_16x16x32_bf16(af[i], b1f[j], pa[i][j], 0, 0, 0);
                    pb[i][j] = __builtin_amdgcn_mfma_f32_16x16x32_bf16(af[i], b2f_[j], pb[i][j], 0, 0, 0);
                }
            __syncthreads();
        }
        // swiglu -> Ps (cols wave*32 .. +31)
#pragma unroll
        for (int i = 0; i < 2; ++i)
#pragma unroll
            for (int r = 0; r < 4; ++r)
#pragma unroll
                for (int j = 0; j < 2; ++j) {
                    float a = pa[i][j][r], b = pb[i][j][r];
                    Ps[(i * 16 + qr + r) * 128 + wave * 32 + j * 16 + fr] = f2b(siluf(a) * b);
                }
        __syncthreads();

        // ---- phase B: oacc += P @ WoutSlice^T (K=128) ----
        for (int k2 = 0; k2 < 128; k2 += 32) {
#pragma unroll
            for (int h = 0; h < 4; ++h) {
                int rW = h * 64 + wave * 16 + rstg;
                gload16(Woutt + (size_t)rW * 1024 + js * 128 + k2 + kc,
                        Bs + (h * 64 + wave * 16) * 32);
            }
            __syncthreads();

            bf16x8 pf[2], wf[4];
#pragma unroll
            for (int i = 0; i < 2; ++i)
                pf[i] = *(const bf16x8*)&Ps[(i * 16 + fr) * 128 + k2 + kb];
#pragma unroll
            for (int j = 0; j < 4; ++j)
                wf[j] = *(const bf16x8*)&Bs[(wave * 64 + j * 16 + fr) * 32 + kb];
#pragma unroll
            for (int i = 0; i < 2; ++i)
#pragma unroll
                for (int j = 0; j < 4; ++j)
                    oacc[i][j] = __builtin_amdgcn_mfma_f32_16x16x32_bf16(pf[i], wf[j], oacc[i][j], 0, 0, 0);
            __syncthreads();
        }
    }

    // ---- epilogue: out = [eae +] A + gate*oacc ----
#pragma unroll
    for (int i = 0; i < 2; ++i)
#pragma unroll
        for (int r = 0; r < 4; ++r) {
            int grow = row0 + i * 16 + qr + r;
            if (grow >= M) continue;
#pragma unroll
            for (int j = 0; j < 4; ++j) {
                int gcol = wave * 64 + j * 16 + fr;
                size_t idx = (size_t)grow * 256 + gcol;
                float v = oacc[i][j][r] * b2f(gate[(size_t)grow * ldg + goff + gcol])
                        + b2f(A[idx]);
                if (eae) v += b2f(eae[idx]);
                out[idx] = v;
            }
        }
}

// ---------------- weight transpose-convert ----------------------------------------------
__global__ __launch_bounds__(256) void k_wconv(
    const float* __restrict__ W, u16* __restrict__ Wt, int K, int N)
{
    int i = blockIdx.x * 256 + threadIdx.x;
    if (i >= K * N) return;
    int n = i / K, k = i - n * K;
    Wt[i] = f2b(W[(size_t)k * N + n]);
}

__global__ __launch_bounds__(256) void k_silu_b16(
    const float* __restrict__ src, u16* __restrict__ dst, long long n4)
{
    long long i = (long long)blockIdx.x * 256 + threadIdx.x;
    if (i >= n4) return;
    float4 v = ((const float4*)src)[i];
    ushort4 o;
    o.x = f2b(siluf(v.x)); o.y = f2b(siluf(v.y)); o.z = f2b(siluf(v.z)); o.w = f2b(siluf(v.w));
    ((ushort4*)dst)[i] = o;
}

// ---------------- LN + modulate (bf16 shift/scale) -> bf16, fp32 input ------------------
__global__ __launch_bounds__(256) void k_ln_mod_b16(
    const float* __restrict__ X, u16* __restrict__ Y, int M,
    const u16* __restrict__ ssb, int ldss, int shoff, int scoff)
{
    int row = (blockIdx.x << 2) + (threadIdx.x >> 6);
    if (row >= M) return;
    int lane = threadIdx.x & 63;
    const float* xr = X + (size_t)row * HID + lane * 4;
    float x0 = xr[0], x1 = xr[1], x2 = xr[2], x3 = xr[3];
    float s = x0 + x1 + x2 + x3;
    float q = x0 * x0 + x1 * x1 + x2 * x2 + x3 * x3;
#pragma unroll
    for (int o = 32; o; o >>= 1) { s += __shfl_xor(s, o, 64); q += __shfl_xor(q, o, 64); }
    float m = s * (1.f / HID);
    float r = rsqrtf(q * (1.f / HID) - m * m + 1e-6f);
    const u16* sp = ssb + (size_t)row * ldss;
    ushort4 sh = *(const ushort4*)(sp + shoff + lane * 4);
    ushort4 sc = *(const ushort4*)(sp + scoff + lane * 4);
    ushort4 o;
    o.x = f2b((x0 - m) * r * (1.f + b2f(sc.x)) + b2f(sh.x));
    o.y = f2b((x1 - m) * r * (1.f + b2f(sc.y)) + b2f(sh.y));
    o.z = f2b((x2 - m) * r * (1.f + b2f(sc.z)) + b2f(sh.z));
    o.w = f2b((x3 - m) * r * (1.f + b2f(sc.w)) + b2f(sh.w));
    ((ushort4*)(Y + (size_t)row * HID))[lane] = o;
}

// ---------------- LN + modulate, bf16 input variant -------------------------------------
__global__ __launch_bounds__(256) void k_ln_mod_b16src(
    const u16* __restrict__ X, u16* __restrict__ Y, int M,
    const u16* __restrict__ ssb, int ldss, int shoff, int scoff)
{
    int row = (blockIdx.x << 2) + (threadIdx.x >> 6);
    if (row >= M) return;
    int lane = threadIdx.x & 63;
    ushort4 xv = ((const ushort4*)(X + (size_t)row * HID))[lane];
    float x0 = b2f(xv.x), x1 = b2f(xv.y), x2 = b2f(xv.z), x3 = b2f(xv.w);
    float s = x0 + x1 + x2 + x3;
    float q = x0 * x0 + x1 * x1 + x2 * x2 + x3 * x3;
#pragma unroll
    for (int o = 32; o; o >>= 1) { s += __shfl_xor(s, o, 64); q += __shfl_xor(q, o, 64); }
    float m = s * (1.f / HID);
    float r = rsqrtf(q * (1.f / HID) - m * m + 1e-6f);
    const u16* sp = ssb + (size_t)row * ldss;
    ushort4 sh = *(const ushort4*)(sp + shoff + lane * 4);
    ushort4 sc = *(const ushort4*)(sp + scoff + lane * 4);
    ushort4 o;
    o.x = f2b((x0 - m) * r * (1.f + b2f(sc.x)) + b2f(sh.x));
    o.y = f2b((x1 - m) * r * (1.f + b2f(sc.y)) + b2f(sh.y));
    o.z = f2b((x2 - m) * r * (1.f + b2f(sc.z)) + b2f(sh.z));
    o.w = f2b((x3 - m) * r * (1.f + b2f(sc.w)) + b2f(sh.w));
    ((ushort4*)(Y + (size_t)row * HID))[lane] = o;
}

// ----- Y(bf16) = modulate( ln(A + gate.*Bv) [*g + b], shift, scale ); fp32 Bv -----------
__global__ __launch_bounds__(256) void k_ln_mod_resid_b16(
    const float* __restrict__ A, const float* __restrict__ Bv, u16* __restrict__ Y, int M,
    const u16* __restrict__ gb, int ldg, int goff,
    const u16* __restrict__ ssb, int ldss, int shoff, int scoff,
    const float* __restrict__ gw, const float* __restrict__ bw)
{
    int row = (blockIdx.x << 2) + (threadIdx.x >> 6);
    if (row >= M) return;
    int lane = threadIdx.x & 63;
    const float* ar = A + (size_t)row * HID + lane * 4;
    const float* br = Bv + (size_t)row * HID + lane * 4;
    ushort4 gp = *(const ushort4*)(gb + (size_t)row * ldg + goff + lane * 4);
    float t0 = ar[0] + b2f(gp.x) * br[0];
    float t1 = ar[1] + b2f(gp.y) * br[1];
    float t2 = ar[2] + b2f(gp.z) * br[2];
    float t3 = ar[3] + b2f(gp.w) * br[3];
    float s = t0 + t1 + t2 + t3;
    float q = t0 * t0 + t1 * t1 + t2 * t2 + t3 * t3;
#pragma unroll
    for (int o = 32; o; o >>= 1) { s += __shfl_xor(s, o, 64); q += __shfl_xor(q, o, 64); }
    float m = s * (1.f / HID);
    float r = rsqrtf(q * (1.f / HID) - m * m + 1e-6f);
    float n0 = (t0 - m) * r, n1 = (t1 - m) * r, n2 = (t2 - m) * r, n3 = (t3 - m) * r;
    if (gw) {
        const float* g4 = gw + lane * 4;
        const float* b4 = bw + lane * 4;
        n0 = n0 * g4[0] + b4[0]; n1 = n1 * g4[1] + b4[1];
        n2 = n2 * g4[2] + b4[2]; n3 = n3 * g4[3] + b4[3];
    }
    const u16* sp = ssb + (size_t)row * ldss;
    ushort4 sh = *(const ushort4*)(sp + shoff + lane * 4);
    ushort4 sc = *(const ushort4*)(sp + scoff + lane * 4);
    ushort4 o;
    o.x = f2b(n0 * (1.f + b2f(sc.x)) + b2f(sh.x));
    o.y = f2b(n1 * (1.f + b2f(sc.y)) + b2f(sh.y));
    o.z = f2b(n2 * (1.f + b2f(sc.z)) + b2f(sh.z));
    o.w = f2b(n3 * (1.f + b2f(sc.w)) + b2f(sh.w));
    ((ushort4*)(Y + (size_t)row * HID))[lane] = o;
}

// ----- same, but Bv is bf16 --------------------------------------------------------------
__global__ __launch_bounds__(256) void k_ln_mod_resid_b16bv(
    const float* __restrict__ A, const u16* __restrict__ Bv, u16* __restrict__ Y, int M,
    const u16* __restrict__ gb, int ldg, int goff,
    const u16* __restrict__ ssb, int ldss, int shoff, int scoff)
{
    int row = (blockIdx.x << 2) + (threadIdx.x >> 6);
    if (row >= M) return;
    int lane = threadIdx.x & 63;
    const float* ar = A + (size_t)row * HID + lane * 4;
    ushort4 bv = ((const ushort4*)(Bv + (size_t)row * HID))[lane];
    ushort4 gp = *(const ushort4*)(gb + (size_t)row * ldg + goff + lane * 4);
    float t0 = ar[0] + b2f(gp.x) * b2f(bv.x);
    float t1 = ar[1] + b2f(gp.y) * b2f(bv.y);
    float t2 = ar[2] + b2f(gp.z) * b2f(bv.z);
    float t3 = ar[3] + b2f(gp.w) * b2f(bv.w);
    float s = t0 + t1 + t2 + t3;
    float q = t0 * t0 + t1 * t1 + t2 * t2 + t3 * t3;
#pragma unroll
    for (int o = 32; o; o >>= 1) { s += __shfl_xor(s, o, 64); q += __shfl_xor(q, o, 64); }
    float m = s * (1.f / HID);
    float r = rsqrtf(q * (1.f / HID) - m * m + 1e-6f);
    float n0 = (t0 - m) * r, n1 = (t1 - m) * r, n2 = (t2 - m) * r, n3 = (t3 - m) * r;
    const u16* sp = ssb + (size_t)row * ldss;
    ushort4 sh = *(const ushort4*)(sp + shoff + lane * 4);
    ushort4 sc = *(const ushort4*)(sp + scoff + lane * 4);
    ushort4 o;
    o.x = f2b(n0 * (1.f + b2f(sc.x)) + b2f(sh.x));
    o.y = f2b(n1 * (1.f + b2f(sc.y)) + b2f(sh.y));
    o.z = f2b(n2 * (1.f + b2f(sc.z)) + b2f(sh.z));
    o.w = f2b(n3 * (1.f + b2f(sc.w)) + b2f(sh.w));
    ((ushort4*)(Y + (size_t)row * HID))[lane] = o;
}

// ---------------- CSR build ------------------------------------------------------------
__global__ __launch_bounds__(256) void k_hist(
    const int* __restrict__ tgt, int* __restrict__ counts, int E)
{
    int i = blockIdx.x * 256 + threadIdx.x;
    if (i < E) atomicAdd(&counts[tgt[i]], 1);
}

__global__ __launch_bounds__(256) void k_scan(
    const int* __restrict__ counts, int* __restrict__ offsets, int Nn)
{
    __shared__ int part[256];
    __shared__ int pref[257];
    int t = threadIdx.x;
    int chunk = (Nn + 255) / 256;
    int lo = t * chunk, hi = imin(lo + chunk, Nn);
    int s = 0;
    for (int i = lo; i < hi; ++i) s += counts[i];
    part[t] = s;
    __syncthreads();
    if (t == 0) {
        int run = 0;
        for (int i = 0; i < 256; ++i) { pref[i] = run; run += part[i]; }
        pref[256] = run;
        offsets[Nn] = run;
    }
    __syncthreads();
    int run = pref[t];
    for (int i = lo; i < hi; ++i) { offsets[i] = run; run += counts[i]; }
}

__global__ __launch_bounds__(256) void k_scatter(
    const int* __restrict__ tgt, int* __restrict__ cursor,
    int* __restrict__ eidlist, int E)
{
    int i = blockIdx.x * 256 + threadIdx.x;
    if (i < E) {
        int pos = atomicAdd(&cursor[tgt[i]], 1);
        eidlist[pos] = i;
    }
}

__global__ __launch_bounds__(256) void k_amax_den(
    const float* __restrict__ alpha, const int* __restrict__ offsets,
    const int* __restrict__ eidlist, float* __restrict__ amaxF,
    float* __restrict__ invden, int NH8)
{
    int i = blockIdx.x * 256 + threadIdx.x;
    if (i >= NH8) return;
    int n = i >> 3, h = i & 7;
    int b = offsets[n], e = offsets[n + 1];
    float m = -1e30f;
    for (int k = b; k < e; ++k) m = fmaxf(m, alpha[(size_t)eidlist[k] * 8 + h]);
    float s = 0.f;
    for (int k = b; k < e; ++k) s += __expf(alpha[(size_t)eidlist[k] * 8 + h] - m);
    amaxF[i] = m;
    invden[i] = (s > 0.f) ? 1.f / s : 0.f;
}

__global__ __launch_bounds__(256) void k_norm(
    float* __restrict__ alpha, const float* __restrict__ amaxF,
    const float* __restrict__ invden, const int* __restrict__ tgt, int EH)
{
    int i = blockIdx.x * 256 + threadIdx.x;
    if (i >= EH) return;
    int e = i >> 3, h = i & 7;
    int g = tgt[e];
    alpha[i] = __expf(alpha[i] - amaxF[(size_t)g * 8 + h]) * invden[(size_t)g * 8 + h];
}

__global__ __launch_bounds__(256) void attn_msg_csr(
    const u16* __restrict__ qkv, const u16* __restrict__ e1b,
    const float* __restrict__ alpha, const int* __restrict__ offsets,
    const int* __restrict__ eidlist, float* __restrict__ hattn)
{
    int n = blockIdx.x;
    int c = threadIdx.x;
    int h = c >> 5;
    int b = offsets[n], e = offsets[n + 1];
    float acc = 0.f;
    for (int k = b; k < e; ++k) {
        int eid = eidlist[k];
        float w = alpha[(size_t)eid * 8 + h];
        acc += b2f(e1b[(size_t)eid * 256 + c]) * w;
    }
    hattn[(size_t)n * 256 + c] = b2f(qkv[(size_t)n * 768 + 512 + c]) * acc;
}

// ---------------------------------------------------------------------------------------
static inline void gemm(hipStream_t st, const u16* A, int lda, const u16* Bt, int ldb,
                        void* C, int ldc, int M, int N, int K,
                        const float* bias, int act, int obf16)
{
    dim3 g(N / 128, (M + 63) / 64);
    hipLaunchKernelGGL(gemm_mfma, g, dim3(256), 0, st, A, lda, Bt, ldb, C, ldc, M, N, K,
                       bias, act, obf16);
}

extern "C" void kernel_launch(void* const* d_in, const int* in_sizes, int n_in,
                              void* d_out, int out_size, void* d_ws, size_t ws_size,
                              hipStream_t stream)
{
    const int Nn = in_sizes[0];
    const int E = in_sizes[3] / HID;

    const float* x        = (const float*)d_in[1];
    const float* t_emb_h  = (const float*)d_in[2];
    const float* edge_attr= (const float*)d_in[3];
    const int*   eidx     = (const int*)d_in[4];
    const float* t_emb_e  = (const float*)d_in[5];
    const float* dist     = (const float*)d_in[6];
    const float* W_ee     = (const float*)d_in[7];
    const float* b_ee     = (const float*)d_in[8];
    const float* W_ad     = (const float*)d_in[9];
    const float* b_ad     = (const float*)d_in[10];
    const float* W_ade    = (const float*)d_in[11];
    const float* b_ade    = (const float*)d_in[12];
    const float* W_qkv    = (const float*)d_in[13];
    const float* W_e0     = (const float*)d_in[14];
    const float* W_e1     = (const float*)d_in[15];
    const float* W_n2e    = (const float*)d_in[16];
    const float* b_n2e    = (const float*)d_in[17];
    const float* g_ln     = (const float*)d_in[18];
    const float* b_ln     = (const float*)d_in[19];
    const float* W_f12    = (const float*)d_in[20];
    const float* W_fout   = (const float*)d_in[21];
    const float* W_fe12   = (const float*)d_in[22];
    const float* W_feout  = (const float*)d_in[23];

    const int* src = eidx;
    const int* tgt = eidx + E;

    float* outN = (float*)d_out;
    float* outE = (float*)d_out + (size_t)Nn * 256;

    // ---- persistent workspace ----
    char* W = (char*)d_ws;
    size_t off = 0;
    auto alloc = [&](size_t bytes) -> size_t {
        size_t o = off; off += (bytes + 255) & ~(size_t)255; return o;
    };
    float*    alpha = (float*)(W + alloc((size_t)E * 8 * 4));
    float*    amaxF = (float*)(W + alloc((size_t)Nn * 8 * 4));
    float*    invden= (float*)(W + alloc((size_t)Nn * 8 * 4));
    float*    hat   = (float*)(W + alloc((size_t)Nn * 256 * 4));
    int*      offs  = (int*)(W + alloc((size_t)(Nn + 1) * 4));
    int*      cursor= (int*)(W + alloc((size_t)Nn * 4));
    int*      eidl  = (int*)(W + alloc((size_t)E * 4));
    u16*      qkvb  = (u16*)(W + alloc((size_t)Nn * 768 * 2));
    u16*      sth   = (u16*)(W + alloc((size_t)Nn * 256 * 2));
    u16*      steb  = (u16*)(W + alloc((size_t)E * 256 * 2));    // silu(t_emb_e)
    u16*      eaeb  = (u16*)(W + alloc((size_t)E * 256 * 2));    // edge_attr_e (bf16)
    u16*      e1b   = (u16*)(W + alloc((size_t)E * 256 * 2));    // e_mod @ W_e1
    u16*      adnb  = (u16*)(W + alloc((size_t)Nn * 1536 * 2));
    u16*      xmb   = (u16*)(W + alloc((size_t)Nn * 256 * 2));
    u16*      h2nb  = (u16*)(W + alloc((size_t)Nn * 256 * 2));
    // bf16 transposed weights (N x K)
    u16* weet   = (u16*)(W + alloc((size_t)256 * 384 * 2));
    u16* wadt   = (u16*)(W + alloc((size_t)1536 * 256 * 2));
    u16* wadet  = (u16*)(W + alloc((size_t)1536 * 256 * 2));
    u16* wqkvt  = (u16*)(W + alloc((size_t)768 * 256 * 2));
    u16* we01t  = (u16*)(W + alloc((size_t)512 * 256 * 2));
    u16* wn2et  = (u16*)(W + alloc((size_t)256 * 256 * 2));
    u16* wf12t  = (u16*)(W + alloc((size_t)2048 * 256 * 2));
    u16* wfoutt = (u16*)(W + alloc((size_t)256 * 1024 * 2));
    u16* wfe12t = (u16*)(W + alloc((size_t)2048 * 256 * 2));
    u16* wfeoutt= (u16*)(W + alloc((size_t)256 * 1024 * 2));

    char* pool = W + off;
    size_t poolB = (ws_size > off) ? (ws_size - off) : 0;
    auto chunkRowsB = [&](size_t bytesPerRow, int total) -> int {
        long c = (long)(poolB / bytesPerRow);
        c = (c / 256) * 256;
        if (c < 256) c = 256;
        if (c > total) c = (long)total;
        return (int)c;
    };

    // ---- CSR build by tgt ----
    hipMemsetAsync(cursor, 0, (size_t)Nn * 4, stream);
    hipLaunchKernelGGL(k_hist, dim3((E + 255) / 256), dim3(256), 0, stream, tgt, cursor, E);
    hipLaunchKernelGGL(k_scan, dim3(1), dim3(256), 0, stream, cursor, offs, Nn);
    hipMemcpyAsync(cursor, offs, (size_t)Nn * 4, hipMemcpyDeviceToDevice, stream);
    hipLaunchKernelGGL(k_scatter, dim3((E + 255) / 256), dim3(256), 0, stream,
                       tgt, cursor, eidl, E);

    // ---- weight conversion ----
    {
        struct WC { const float* w; u16* wt; int K, N; } wl[] = {
            { W_ee,    weet,   384, 256 },
            { W_ad,    wadt,   256, 1536 },
            { W_ade,   wadet,  256, 1536 },
            { W_qkv,   wqkvt,  256, 768 },
            { W_e0,    we01t,  256, 256 },
            { W_e1,    we01t + 256 * 256, 256, 256 },
            { W_n2e,   wn2et,  256, 256 },
            { W_f12,   wf12t,  256, 2048 },
            { W_fout,  wfoutt, 1024, 256 },
            { W_fe12,  wfe12t, 256, 2048 },
            { W_feout, wfeoutt,1024, 256 },
        };
        for (auto& e : wl) {
            int cnt = e.K * e.N;
            hipLaunchKernelGGL(k_wconv, dim3((cnt + 255) / 256), dim3(256), 0, stream,
                               e.w, e.wt, e.K, e.N);
        }
    }

    // silu conversions (persistent)
    hipLaunchKernelGGL(k_silu_b16, dim3((unsigned)(((long long)Nn * 64 + 255) / 256)), dim3(256),
                       0, stream, t_emb_h, sth, (long long)Nn * 64);
    hipLaunchKernelGGL(k_silu_b16, dim3((unsigned)(((long long)E * 64 + 255) / 256)), dim3(256),
                       0, stream, t_emb_e, steb, (long long)E * 64);

    // ---- phase 1: node pre ----
    gemm(stream, sth, 256, wadt, 256, adnb, 1536, Nn, 1536, 256, b_ad, 0, 1);
    hipLaunchKernelGGL(k_ln_mod_b16, dim3((Nn + 3) / 4), dim3(256), 0, stream,
                       x, xmb, Nn, adnb, 1536, 0, 256);
    gemm(stream, xmb, 256, wqkvt, 256, qkvb, 768, Nn, 768, 256, nullptr, 0, 1);

    // ---- phase 2: edge pre ----
    {
        int C = chunkRowsB(1024 + 512, E);
        char* p = pool;
        u16* emsb = (u16*)p; p += (size_t)C * 1024;   // adaln_e[:,0:512) (bf16)
        u16* emod = (u16*)p;                          // C x 256 bf16
        for (int s = 0; s < E; s += C) {
            int cc = (E - s < C) ? (E - s) : C;
            hipLaunchKernelGGL(gemm_cat, dim3(2, (cc + 63) / 64), dim3(256), 0, stream,
                               edge_attr + (size_t)s * 256, dist + (size_t)s * 128,
                               weet, eaeb + (size_t)s * 256, cc, b_ee);
            gemm(stream, steb + (size_t)s * 256, 256, wadet, 256, emsb, 512, cc, 512, 256,
                 b_ade, 0, 1);
            hipLaunchKernelGGL(k_ln_mod_b16src, dim3((cc + 3) / 4), dim3(256), 0, stream,
                               eaeb + (size_t)s * 256, emod, cc, emsb, 512, 0, 256);
            hipLaunchKernelGGL(gemm_e01, dim3(4, (cc + 63) / 64), dim3(256), 0, stream,
                               emod, we01t, e1b + (size_t)s * 256, cc,
                               qkvb, src + s, tgt + s, alpha + (size_t)s * 8);
        }
    }

    // ---- phase 3: softmax stats + normalize ----
    hipLaunchKernelGGL(k_amax_den, dim3((Nn * 8 + 255) / 256), dim3(256), 0, stream,
                       alpha, offs, eidl, amaxF, invden, Nn * 8);
    hipLaunchKernelGGL(k_norm, dim3((E * 8 + 255) / 256), dim3(256), 0, stream,
                       alpha, amaxF, invden, tgt, E * 8);

    // ---- phase 4: message pass via CSR ----
    hipLaunchKernelGGL(attn_msg_csr, dim3(Nn), dim3(256), 0, stream,
                       qkvb, e1b, alpha, offs, eidl, hat);

    // ---- phase 5: node finish (fused FFN) ----
    hipLaunchKernelGGL(k_ln_mod_resid_b16, dim3((Nn + 3) / 4), dim3(256), 0, stream,
                       x, hat, h2nb, Nn, adnb, 1536, 512, adnb, 1536, 768, 1024, g_ln, b_ln);
    hipLaunchKernelGGL(gemm_ffn_full, dim3((Nn + 31) / 32), dim3(256), 0, stream,
                       h2nb, wf12t, wfoutt, (const u16*)nullptr,
                       adnb, 1536, 1280, outN, Nn);

    // ---- phase 6: edge finish (fused FFN) ----
    {
        int C = chunkRowsB(2048 + 512 + 512, E);
        char* p = pool;
        u16*   em2b = (u16*)p;  p += (size_t)C * 2048;   // adaln_e[:,512:1536)
        u16*   hep  = (u16*)p;  p += (size_t)C * 512;    // bf16
        u16*   h2e  = (u16*)p;                           // bf16
        for (int s = 0; s < E; s += C) {
            int cc = (E - s < C) ? (E - s) : C;
            hipLaunchKernelGGL(gemm_gsum, dim3(2, (cc + 63) / 64), dim3(256), 0, stream,
                               hat, src + s, tgt + s, wn2et, hep, cc, b_n2e);
            gemm(stream, steb + (size_t)s * 256, 256, wadet + 512 * 256, 256, em2b, 1024,
                 cc, 1024, 256, b_ade + 512, 0, 1);
            hipLaunchKernelGGL(k_ln_mod_resid_b16bv, dim3((cc + 3) / 4), dim3(256), 0, stream,
                               edge_attr + (size_t)s * 256, hep, h2e, cc,
                               em2b, 1024, 0, em2b, 1024, 256, 512);
            hipLaunchKernelGGL(gemm_ffn_full, dim3((cc + 31) / 32), dim3(256), 0, stream,
                               h2e, wfe12t, wfeoutt, eaeb + (size_t)s * 256,
                               em2b, 1024, 768, outE + (size_t)s * 256, cc);
        }
    }
    (void)n_in; (void)out_size;
}

// Round 19
// 1895.263 us; speedup vs baseline: 1.1665x; 1.1665x over previous
//
#include <hip/hip_runtime.h>

#define HID 256

typedef unsigned short u16;
typedef __attribute__((ext_vector_type(8))) short bf16x8;
typedef __attribute__((ext_vector_type(4))) float f32x4;

__device__ __forceinline__ float siluf(float x) { return x / (1.f + __expf(-x)); }
// tanh-approx gelu via sigmoid identity: 0.5x(1+tanh(z)) == x*sigmoid(2z)
__device__ __forceinline__ float geluf(float x) {
    return x / (1.f + __expf(-(1.59576912f * x + 0.07135481f * x * x * x)));
}
__device__ __forceinline__ u16 f2b(float x) {
    unsigned u = __float_as_uint(x);
    unsigned r = u + 0x7FFFu + ((u >> 16) & 1u);
    return (u16)(r >> 16);
}
__device__ __forceinline__ float b2f(u16 h) {
    return __uint_as_float(((unsigned)h) << 16);
}
__device__ __forceinline__ void gload16(const u16* g, u16* l) {
    __builtin_amdgcn_global_load_lds(
        (const __attribute__((address_space(1))) unsigned int*)g,
        (__attribute__((address_space(3))) unsigned int*)l, 16, 0, 0);
}
__device__ __forceinline__ int imin(int a, int b) { return a < b ? a : b; }

union B16x8 { u16 u[8]; uint4 q; };

// ---------------- bf16 MFMA GEMM: C = act(A @ Bt^T + bias) ------------------------------
// A: M x K bf16 (lda). Bt: N x K bf16 (ldb). 64x128 tile, BK=32, 4 waves 2x2 of 32x64.
// act: 1=silu, 2=gelu. N%128==0, K%32==0.
__global__ __launch_bounds__(256) void gemm_mfma(
    const u16* __restrict__ A, int lda,
    const u16* __restrict__ Bt, int ldb,
    void* __restrict__ Cv, int ldc,
    int M, int N, int K,
    const float* __restrict__ bias, int act, int obf16)
{
    __shared__ u16 lds[8192];

    const int tid  = threadIdx.x;
    const int lane = tid & 63;
    const int wave = tid >> 6;
    const int row0 = blockIdx.y * 64;
    const int col0 = blockIdx.x * 128;
    const int wm   = (wave >> 1) * 32;
    const int wn   = (wave & 1) * 64;

    f32x4 acc[2][4];
#pragma unroll
    for (int i = 0; i < 2; ++i)
#pragma unroll
        for (int j = 0; j < 4; ++j) acc[i][j] = (f32x4)0.0f;

    const int kc = (lane & 3) * 8;
    const int rr  = wave * 16 + (lane >> 2);
    const int rb1 = (wave + 4) * 16 + (lane >> 2);
    const u16* pa  = A + (size_t)imin(row0 + rr, M - 1) * lda + kc;
    const u16* pb0 = Bt + (size_t)(col0 + rr) * ldb + kc;
    const u16* pb1 = Bt + (size_t)(col0 + rb1) * ldb + kc;
    u16* la  = &lds[wave * 512];
    u16* lb0 = &lds[2048 + wave * 512];
    u16* lb1 = &lds[2048 + (wave + 4) * 512];

    const int kb = (lane >> 4) * 8;
    const int fr = lane & 15;

    for (int k0 = 0; k0 < K; k0 += 32) {
        gload16(pa + k0, la);
        gload16(pb0 + k0, lb0);
        gload16(pb1 + k0, lb1);
        __syncthreads();

        bf16x8 af[2], bfm[4];
#pragma unroll
        for (int i = 0; i < 2; ++i)
            af[i] = *(const bf16x8*)&lds[(wm + i * 16 + fr) * 32 + kb];
#pragma unroll
        for (int j = 0; j < 4; ++j)
            bfm[j] = *(const bf16x8*)&lds[2048 + (wn + j * 16 + fr) * 32 + kb];
#pragma unroll
        for (int i = 0; i < 2; ++i)
#pragma unroll
            for (int j = 0; j < 4; ++j)
                acc[i][j] = __builtin_amdgcn_mfma_f32_16x16x32_bf16(af[i], bfm[j], acc[i][j], 0, 0, 0);
        __syncthreads();
    }

    const int qr = (lane >> 4) * 4;
    if (obf16) {
#pragma unroll
        for (int i = 0; i < 2; ++i)
#pragma unroll
            for (int r = 0; r < 4; ++r)
#pragma unroll
                for (int j = 0; j < 4; ++j) {
                    int lcol = wn + j * 16 + fr;
                    int gcol = col0 + lcol;
                    float v = acc[i][j][r];
                    if (bias) v += bias[gcol];
                    if (act == 2) v = geluf(v);
                    else if (act == 1) v = siluf(v);
                    lds[(wm + i * 16 + qr + r) * 128 + lcol] = f2b(v);
                }
        __syncthreads();
        int row = tid >> 2, cc0 = (tid & 3) * 32;
        int grow = row0 + row;
        if (grow < M) {
            uint4* dst = (uint4*)((u16*)Cv + (size_t)grow * ldc + col0 + cc0);
            const uint4* sp = (const uint4*)&lds[row * 128 + cc0];
            dst[0] = sp[0]; dst[1] = sp[1]; dst[2] = sp[2]; dst[3] = sp[3];
        }
    } else {
        float* Cf = (float*)Cv;
#pragma unroll
        for (int i = 0; i < 2; ++i)
#pragma unroll
            for (int r = 0; r < 4; ++r) {
                int grow = row0 + wm + i * 16 + qr + r;
                if (grow >= M) continue;
#pragma unroll
                for (int j = 0; j < 4; ++j) {
                    int gcol = col0 + wn + j * 16 + fr;
                    float v = acc[i][j][r];
                    if (bias) v += bias[gcol];
                    if (act == 2) v = geluf(v);
                    else if (act == 1) v = siluf(v);
                    Cf[(size_t)grow * ldc + gcol] = v;
                }
            }
    }
}

// ------- gemm_e01: fused [gelu(emod@We0)->alpha | emod@We1->e1b] ------------------------
// A: emod M x 256 bf16. Bt: we01t 512 x 256. grid (4, ceil(M/64)).
// bx<2: gelu cols (heads bx*4..bx*4+3) -> compute alpha[e,h] in-epilogue, NO global store.
// bx>=2: plain -> store to e1b (M x 256).
__global__ __launch_bounds__(256) void gemm_e01(
    const u16* __restrict__ A, const u16* __restrict__ Bt,
    u16* __restrict__ e1b, int M,
    const u16* __restrict__ qkv, const int* __restrict__ srcI, const int* __restrict__ tgtI,
    float* __restrict__ alpha)
{
    __shared__ u16 lds[8192];

    const int tid  = threadIdx.x;
    const int lane = tid & 63;
    const int wave = tid >> 6;
    const int row0 = blockIdx.y * 64;
    const int bx   = blockIdx.x;
    const int col0 = bx * 128;
    const int wm   = (wave >> 1) * 32;
    const int wn   = (wave & 1) * 64;

    f32x4 acc[2][4];
#pragma unroll
    for (int i = 0; i < 2; ++i)
#pragma unroll
        for (int j = 0; j < 4; ++j) acc[i][j] = (f32x4)0.0f;

    const int kc = (lane & 3) * 8;
    const int rr  = wave * 16 + (lane >> 2);
    const int rb1 = (wave + 4) * 16 + (lane >> 2);
    const u16* pa  = A + (size_t)imin(row0 + rr, M - 1) * 256 + kc;
    const u16* pb0 = Bt + (size_t)(col0 + rr) * 256 + kc;
    const u16* pb1 = Bt + (size_t)(col0 + rb1) * 256 + kc;
    u16* la  = &lds[wave * 512];
    u16* lb0 = &lds[2048 + wave * 512];
    u16* lb1 = &lds[2048 + (wave + 4) * 512];

    const int kb = (lane >> 4) * 8;
    const int fr = lane & 15;

    for (int k0 = 0; k0 < 256; k0 += 32) {
        gload16(pa + k0, la);
        gload16(pb0 + k0, lb0);
        gload16(pb1 + k0, lb1);
        __syncthreads();

        bf16x8 af[2], bfm[4];
#pragma unroll
        for (int i = 0; i < 2; ++i)
            af[i] = *(const bf16x8*)&lds[(wm + i * 16 + fr) * 32 + kb];
#pragma unroll
        for (int j = 0; j < 4; ++j)
            bfm[j] = *(const bf16x8*)&lds[2048 + (wn + j * 16 + fr) * 32 + kb];
#pragma unroll
        for (int i = 0; i < 2; ++i)
#pragma unroll
            for (int j = 0; j < 4; ++j)
                acc[i][j] = __builtin_amdgcn_mfma_f32_16x16x32_bf16(af[i], bfm[j], acc[i][j], 0, 0, 0);
        __syncthreads();
    }

    const int qr = (lane >> 4) * 4;
    const bool isE0 = (bx < 2);
#pragma unroll
    for (int i = 0; i < 2; ++i)
#pragma unroll
        for (int r = 0; r < 4; ++r)
#pragma unroll
            for (int j = 0; j < 4; ++j) {
                int lcol = wn + j * 16 + fr;
                float v = acc[i][j][r];
                if (isE0) v = geluf(v);
                lds[(wm + i * 16 + qr + r) * 128 + lcol] = f2b(v);
            }
    __syncthreads();
    int row = tid >> 2, cc0 = (tid & 3) * 32;
    int grow = row0 + row;
    if (grow < M) {
        if (isE0) {
            int head = bx * 4 + (tid & 3);
            const u16* qv = qkv + (size_t)srcI[grow] * 768 + head * 32;
            const u16* kv = qkv + (size_t)tgtI[grow] * 768 + 256 + head * 32;
            const u16* gv = &lds[row * 128 + cc0];
            float s = 0.f;
#pragma unroll
            for (int c = 0; c < 32; ++c)
                s += b2f(gv[c]) * b2f(qv[c]) * b2f(kv[c]);
            alpha[(size_t)grow * 8 + head] = s * 0.17677669529663687f;
        } else {
            uint4* dst = (uint4*)(e1b + (size_t)grow * 256 + (col0 - 256) + cc0);
            const uint4* sp = (const uint4*)&lds[row * 128 + cc0];
            dst[0] = sp[0]; dst[1] = sp[1]; dst[2] = sp[2]; dst[3] = sp[3];
        }
    }
}

// ------- gemm_cat: C(bf16) = [A1(fp32,256) | A2(fp32,128)] @ Bt^T + bias ----------------
__global__ __launch_bounds__(256) void gemm_cat(
    const float* __restrict__ A1, const float* __restrict__ A2,
    const u16* __restrict__ Bt,
    u16* __restrict__ C, int M, const float* __restrict__ bias)
{
    __shared__ u16 lds[8192];

    const int tid  = threadIdx.x;
    const int lane = tid & 63;
    const int wave = tid >> 6;
    const int row0 = blockIdx.y * 64;
    const int col0 = blockIdx.x * 128;
    const int wm   = (wave >> 1) * 32;
    const int wn   = (wave & 1) * 64;

    f32x4 acc[2][4];
#pragma unroll
    for (int i = 0; i < 2; ++i)
#pragma unroll
        for (int j = 0; j < 4; ++j) acc[i][j] = (f32x4)0.0f;

    const int kc = (lane & 3) * 8;
    const int rr  = wave * 16 + (lane >> 2);
    const int rb1 = (wave + 4) * 16 + (lane >> 2);
    const int gr  = imin(row0 + rr, M - 1);
    const u16* pb0 = Bt + (size_t)(col0 + rr) * 384 + kc;
    const u16* pb1 = Bt + (size_t)(col0 + rb1) * 384 + kc;
    u16* lb0 = &lds[2048 + wave * 512];
    u16* lb1 = &lds[2048 + (wave + 4) * 512];
    u16* laD = &lds[wave * 512 + (lane & 63) * 8];

    const int kb = (lane >> 4) * 8;
    const int fr = lane & 15;

    for (int k0 = 0; k0 < 384; k0 += 32) {
        int kk = k0 + kc;
        const float* sp = (kk < 256) ? (A1 + (size_t)gr * 256 + kk)
                                     : (A2 + (size_t)gr * 128 + (kk - 256));
        float4 v0 = *(const float4*)sp;
        float4 v1 = *(const float4*)(sp + 4);
        gload16(pb0 + k0, lb0);
        gload16(pb1 + k0, lb1);
        B16x8 t;
        t.u[0] = f2b(v0.x); t.u[1] = f2b(v0.y); t.u[2] = f2b(v0.z); t.u[3] = f2b(v0.w);
        t.u[4] = f2b(v1.x); t.u[5] = f2b(v1.y); t.u[6] = f2b(v1.z); t.u[7] = f2b(v1.w);
        *(uint4*)laD = t.q;
        __syncthreads();

        bf16x8 af[2], bfm[4];
#pragma unroll
        for (int i = 0; i < 2; ++i)
            af[i] = *(const bf16x8*)&lds[(wm + i * 16 + fr) * 32 + kb];
#pragma unroll
        for (int j = 0; j < 4; ++j)
            bfm[j] = *(const bf16x8*)&lds[2048 + (wn + j * 16 + fr) * 32 + kb];
#pragma unroll
        for (int i = 0; i < 2; ++i)
#pragma unroll
            for (int j = 0; j < 4; ++j)
                acc[i][j] = __builtin_amdgcn_mfma_f32_16x16x32_bf16(af[i], bfm[j], acc[i][j], 0, 0, 0);
        __syncthreads();
    }

    const int qr = (lane >> 4) * 4;
#pragma unroll
    for (int i = 0; i < 2; ++i)
#pragma unroll
        for (int r = 0; r < 4; ++r)
#pragma unroll
            for (int j = 0; j < 4; ++j) {
                int lcol = wn + j * 16 + fr;
                float v = acc[i][j][r] + bias[col0 + lcol];
                lds[(wm + i * 16 + qr + r) * 128 + lcol] = f2b(v);
            }
    __syncthreads();
    int row = tid >> 2, cc0 = (tid & 3) * 32;
    int grow = row0 + row;
    if (grow < M) {
        uint4* dst = (uint4*)(C + (size_t)grow * 256 + col0 + cc0);
        const uint4* sp = (const uint4*)&lds[row * 128 + cc0];
        dst[0] = sp[0]; dst[1] = sp[1]; dst[2] = sp[2]; dst[3] = sp[3];
    }
}

// ------- gemm_gsum: C(bf16) = (hat[src]+hat[tgt]) @ Wn2e^T + b_n2e ----------------------
__global__ __launch_bounds__(256) void gemm_gsum(
    const float* __restrict__ hat, const int* __restrict__ srcI, const int* __restrict__ tgtI,
    const u16* __restrict__ Bt,
    u16* __restrict__ C, int M, const float* __restrict__ bias)
{
    __shared__ u16 lds[8192];

    const int tid  = threadIdx.x;
    const int lane = tid & 63;
    const int wave = tid >> 6;
    const int row0 = blockIdx.y * 64;
    const int col0 = blockIdx.x * 128;
    const int wm   = (wave >> 1) * 32;
    const int wn   = (wave & 1) * 64;

    f32x4 acc[2][4];
#pragma unroll
    for (int i = 0; i < 2; ++i)
#pragma unroll
        for (int j = 0; j < 4; ++j) acc[i][j] = (f32x4)0.0f;

    const int kc = (lane & 3) * 8;
    const int rr  = wave * 16 + (lane >> 2);
    const int rb1 = (wave + 4) * 16 + (lane >> 2);
    const int gr  = imin(row0 + rr, M - 1);
    const float* ps = hat + (size_t)srcI[gr] * 256 + kc;
    const float* pt = hat + (size_t)tgtI[gr] * 256 + kc;
    const u16* pb0 = Bt + (size_t)(col0 + rr) * 256 + kc;
    const u16* pb1 = Bt + (size_t)(col0 + rb1) * 256 + kc;
    u16* lb0 = &lds[2048 + wave * 512];
    u16* lb1 = &lds[2048 + (wave + 4) * 512];
    u16* laD = &lds[wave * 512 + (lane & 63) * 8];

    const int kb = (lane >> 4) * 8;
    const int fr = lane & 15;

    for (int k0 = 0; k0 < 256; k0 += 32) {
        float4 a0 = *(const float4*)(ps + k0);
        float4 a1 = *(const float4*)(ps + k0 + 4);
        float4 b0 = *(const float4*)(pt + k0);
        float4 b1 = *(const float4*)(pt + k0 + 4);
        gload16(pb0 + k0, lb0);
        gload16(pb1 + k0, lb1);
        B16x8 t;
        t.u[0] = f2b(a0.x + b0.x); t.u[1] = f2b(a0.y + b0.y);
        t.u[2] = f2b(a0.z + b0.z); t.u[3] = f2b(a0.w + b0.w);
        t.u[4] = f2b(a1.x + b1.x); t.u[5] = f2b(a1.y + b1.y);
        t.u[6] = f2b(a1.z + b1.z); t.u[7] = f2b(a1.w + b1.w);
        *(uint4*)laD = t.q;
        __syncthreads();

        bf16x8 af[2], bfm[4];
#pragma unroll
        for (int i = 0; i < 2; ++i)
            af[i] = *(const bf16x8*)&lds[(wm + i * 16 + fr) * 32 + kb];
#pragma unroll
        for (int j = 0; j < 4; ++j)
            bfm[j] = *(const bf16x8*)&lds[2048 + (wn + j * 16 + fr) * 32 + kb];
#pragma unroll
        for (int i = 0; i < 2; ++i)
#pragma unroll
            for (int j = 0; j < 4; ++j)
                acc[i][j] = __builtin_amdgcn_mfma_f32_16x16x32_bf16(af[i], bfm[j], acc[i][j], 0, 0, 0);
        __syncthreads();
    }

    const int qr = (lane >> 4) * 4;
#pragma unroll
    for (int i = 0; i < 2; ++i)
#pragma unroll
        for (int r = 0; r < 4; ++r)
#pragma unroll
            for (int j = 0; j < 4; ++j) {
                int lcol = wn + j * 16 + fr;
                float v = acc[i][j][r] + bias[col0 + lcol];
                lds[(wm + i * 16 + qr + r) * 128 + lcol] = f2b(v);
            }
    __syncthreads();
    int row = tid >> 2, cc0 = (tid & 3) * 32;
    int grow = row0 + row;
    if (grow < M) {
        uint4* dst = (uint4*)(C + (size_t)grow * 256 + col0 + cc0);
        const uint4* sp = (const uint4*)&lds[row * 128 + cc0];
        dst[0] = sp[0]; dst[1] = sp[1]; dst[2] = sp[2]; dst[3] = sp[3];
    }
}

// ---------------- fused FFN12 + swiglu ---------------------------------------------------
__global__ __launch_bounds__(256) void gemm_ffn12(
    const u16* __restrict__ A, const u16* __restrict__ Wt,
    u16* __restrict__ C, int M)
{
    __shared__ u16 sm[6144];
    u16* lsA = sm;
    u16* lsB1 = sm + 2048;
    u16* lsB2 = sm + 4096;

    const int tid  = threadIdx.x;
    const int lane = tid & 63;
    const int wave = tid >> 6;
    const int row0 = blockIdx.y * 64;
    const int col0 = blockIdx.x * 64;
    const int wm   = (wave >> 1) * 32;
    const int wn   = (wave & 1) * 32;

    f32x4 accA[2][2], accB[2][2];
#pragma unroll
    for (int i = 0; i < 2; ++i)
#pragma unroll
        for (int j = 0; j < 2; ++j) { accA[i][j] = (f32x4)0.0f; accB[i][j] = (f32x4)0.0f; }

    const int kc = (lane & 3) * 8;
    const int rr = wave * 16 + (lane >> 2);
    const u16* pa  = A + (size_t)imin(row0 + rr, M - 1) * 256 + kc;
    const u16* pb1 = Wt + (size_t)(col0 + rr) * 256 + kc;
    const u16* pb2 = Wt + (size_t)(1024 + col0 + rr) * 256 + kc;
    u16* la  = &lsA[wave * 512];
    u16* lb1 = &lsB1[wave * 512];
    u16* lb2 = &lsB2[wave * 512];

    const int kb = (lane >> 4) * 8;
    const int fr = lane & 15;

#pragma unroll 1
    for (int k0 = 0; k0 < 256; k0 += 32) {
        gload16(pa + k0, la);
        gload16(pb1 + k0, lb1);
        gload16(pb2 + k0, lb2);
        __syncthreads();

        bf16x8 af[2], b1f[2], b2f_[2];
#pragma unroll
        for (int i = 0; i < 2; ++i)
            af[i] = *(const bf16x8*)&lsA[(wm + i * 16 + fr) * 32 + kb];
#pragma unroll
        for (int j = 0; j < 2; ++j) {
            b1f[j] = *(const bf16x8*)&lsB1[(wn + j * 16 + fr) * 32 + kb];
            b2f_[j] = *(const bf16x8*)&lsB2[(wn + j * 16 + fr) * 32 + kb];
        }
#pragma unroll
        for (int i = 0; i < 2; ++i)
#pragma unroll
            for (int j = 0; j < 2; ++j) {
                accA[i][j] = __builtin_amdgcn_mfma_f32_16x16x32_bf16(af[i], b1f[j], accA[i][j], 0, 0, 0);
                accB[i][j] = __builtin_amdgcn_mfma_f32_16x16x32_bf16(af[i], b2f_[j], accB[i][j], 0, 0, 0);
            }
        __syncthreads();
    }

    const int qr = (lane >> 4) * 4;
#pragma unroll
    for (int i = 0; i < 2; ++i)
#pragma unroll
        for (int r = 0; r < 4; ++r)
#pragma unroll
            for (int j = 0; j < 2; ++j) {
                float a = accA[i][j][r], b = accB[i][j][r];
                sm[(wm + i * 16 + qr + r) * 64 + wn + j * 16 + fr] = f2b(siluf(a) * b);
            }
    __syncthreads();
    int row = tid >> 2, cc0 = (tid & 3) * 16;
    int grow = row0 + row;
    if (grow < M) {
        uint4* dst = (uint4*)(C + (size_t)grow * 1024 + col0 + cc0);
        const uint4* sp = (const uint4*)&sm[row * 64 + cc0];
        dst[0] = sp[0]; dst[1] = sp[1];
    }
}

// ---------------- fused FFN-out + final: out = [eae(bf16) +] h2 + gate*(A@Wout) --------
__global__ __launch_bounds__(256) void gemm_out_final(
    const u16* __restrict__ A, const u16* __restrict__ Bt,
    const u16* __restrict__ eae, const u16* __restrict__ h2,
    const u16* __restrict__ gate, int ldg, int goff,
    float* __restrict__ out, int M)
{
    __shared__ u16 lds[6144];

    const int tid  = threadIdx.x;
    const int lane = tid & 63;
    const int wave = tid >> 6;
    const int row0 = blockIdx.y * 64;
    const int col0 = blockIdx.x * 128;
    const int wm   = (wave >> 1) * 32;
    const int wn   = (wave & 1) * 64;

    f32x4 acc[2][4];
#pragma unroll
    for (int i = 0; i < 2; ++i)
#pragma unroll
        for (int j = 0; j < 4; ++j) acc[i][j] = (f32x4)0.0f;

    const int kc = (lane & 3) * 8;
    const int rr = wave * 16 + (lane >> 2);
    const int rb1 = (wave + 4) * 16 + (lane >> 2);
    const u16* pa  = A + (size_t)imin(row0 + rr, M - 1) * 1024 + kc;
    const u16* pb0 = Bt + (size_t)(col0 + rr) * 1024 + kc;
    const u16* pb1 = Bt + (size_t)(col0 + rb1) * 1024 + kc;
    u16* la  = &lds[wave * 512];
    u16* lb0 = &lds[2048 + wave * 512];
    u16* lb1 = &lds[2048 + (wave + 4) * 512];

    const int kb = (lane >> 4) * 8;
    const int fr = lane & 15;

#pragma unroll 1
    for (int k0 = 0; k0 < 1024; k0 += 32) {
        gload16(pa + k0, la);
        gload16(pb0 + k0, lb0);
        gload16(pb1 + k0, lb1);
        __syncthreads();

        bf16x8 af[2], bfm[4];
#pragma unroll
        for (int i = 0; i < 2; ++i)
            af[i] = *(const bf16x8*)&lds[(wm + i * 16 + fr) * 32 + kb];
#pragma unroll
        for (int j = 0; j < 4; ++j)
            bfm[j] = *(const bf16x8*)&lds[2048 + (wn + j * 16 + fr) * 32 + kb];
#pragma unroll
        for (int i = 0; i < 2; ++i)
#pragma unroll
            for (int j = 0; j < 4; ++j)
                acc[i][j] = __builtin_amdgcn_mfma_f32_16x16x32_bf16(af[i], bfm[j], acc[i][j], 0, 0, 0);
        __syncthreads();
    }

    const int qr = (lane >> 4) * 4;
#pragma unroll
    for (int i = 0; i < 2; ++i)
#pragma unroll
        for (int r = 0; r < 4; ++r) {
            int grow = row0 + wm + i * 16 + qr + r;
            if (grow >= M) continue;
#pragma unroll
            for (int j = 0; j < 4; ++j) {
                int gcol = col0 + wn + j * 16 + fr;
                size_t idx = (size_t)grow * 256 + gcol;
                float v = acc[i][j][r] * b2f(gate[(size_t)grow * ldg + goff + gcol]) + b2f(h2[idx]);
                if (eae) v += b2f(eae[idx]);
                out[idx] = v;
            }
        }
}

// ---------------- weight transpose-convert ----------------------------------------------
__global__ __launch_bounds__(256) void k_wconv(
    const float* __restrict__ W, u16* __restrict__ Wt, int K, int N)
{
    int i = blockIdx.x * 256 + threadIdx.x;
    if (i >= K * N) return;
    int n = i / K, k = i - n * K;
    Wt[i] = f2b(W[(size_t)k * N + n]);
}

__global__ __launch_bounds__(256) void k_silu_b16(
    const float* __restrict__ src, u16* __restrict__ dst, long long n4)
{
    long long i = (long long)blockIdx.x * 256 + threadIdx.x;
    if (i >= n4) return;
    float4 v = ((const float4*)src)[i];
    ushort4 o;
    o.x = f2b(siluf(v.x)); o.y = f2b(siluf(v.y)); o.z = f2b(siluf(v.z)); o.w = f2b(siluf(v.w));
    ((ushort4*)dst)[i] = o;
}

// ---------------- LN + modulate (bf16 shift/scale) -> bf16, fp32 input ------------------
__global__ __launch_bounds__(256) void k_ln_mod_b16(
    const float* __restrict__ X, u16* __restrict__ Y, int M,
    const u16* __restrict__ ssb, int ldss, int shoff, int scoff)
{
    int row = (blockIdx.x << 2) + (threadIdx.x >> 6);
    if (row >= M) return;
    int lane = threadIdx.x & 63;
    const float* xr = X + (size_t)row * HID + lane * 4;
    float x0 = xr[0], x1 = xr[1], x2 = xr[2], x3 = xr[3];
    float s = x0 + x1 + x2 + x3;
    float q = x0 * x0 + x1 * x1 + x2 * x2 + x3 * x3;
#pragma unroll
    for (int o = 32; o; o >>= 1) { s += __shfl_xor(s, o, 64); q += __shfl_xor(q, o, 64); }
    float m = s * (1.f / HID);
    float r = rsqrtf(q * (1.f / HID) - m * m + 1e-6f);
    const u16* sp = ssb + (size_t)row * ldss;
    ushort4 sh = *(const ushort4*)(sp + shoff + lane * 4);
    ushort4 sc = *(const ushort4*)(sp + scoff + lane * 4);
    ushort4 o;
    o.x = f2b((x0 - m) * r * (1.f + b2f(sc.x)) + b2f(sh.x));
    o.y = f2b((x1 - m) * r * (1.f + b2f(sc.y)) + b2f(sh.y));
    o.z = f2b((x2 - m) * r * (1.f + b2f(sc.z)) + b2f(sh.z));
    o.w = f2b((x3 - m) * r * (1.f + b2f(sc.w)) + b2f(sh.w));
    ((ushort4*)(Y + (size_t)row * HID))[lane] = o;
}

// ---------------- LN + modulate, bf16 input variant -------------------------------------
__global__ __launch_bounds__(256) void k_ln_mod_b16src(
    const u16* __restrict__ X, u16* __restrict__ Y, int M,
    const u16* __restrict__ ssb, int ldss, int shoff, int scoff)
{
    int row = (blockIdx.x << 2) + (threadIdx.x >> 6);
    if (row >= M) return;
    int lane = threadIdx.x & 63;
    ushort4 xv = ((const ushort4*)(X + (size_t)row * HID))[lane];
    float x0 = b2f(xv.x), x1 = b2f(xv.y), x2 = b2f(xv.z), x3 = b2f(xv.w);
    float s = x0 + x1 + x2 + x3;
    float q = x0 * x0 + x1 * x1 + x2 * x2 + x3 * x3;
#pragma unroll
    for (int o = 32; o; o >>= 1) { s += __shfl_xor(s, o, 64); q += __shfl_xor(q, o, 64); }
    float m = s * (1.f / HID);
    float r = rsqrtf(q * (1.f / HID) - m * m + 1e-6f);
    const u16* sp = ssb + (size_t)row * ldss;
    ushort4 sh = *(const ushort4*)(sp + shoff + lane * 4);
    ushort4 sc = *(const ushort4*)(sp + scoff + lane * 4);
    ushort4 o;
    o.x = f2b((x0 - m) * r * (1.f + b2f(sc.x)) + b2f(sh.x));
    o.y = f2b((x1 - m) * r * (1.f + b2f(sc.y)) + b2f(sh.y));
    o.z = f2b((x2 - m) * r * (1.f + b2f(sc.z)) + b2f(sh.z));
    o.w = f2b((x3 - m) * r * (1.f + b2f(sc.w)) + b2f(sh.w));
    ((ushort4*)(Y + (size_t)row * HID))[lane] = o;
}

// ----- Y(bf16) = modulate( ln(A + gate.*Bv) [*g + b], shift, scale ); fp32 Bv -----------
__global__ __launch_bounds__(256) void k_ln_mod_resid_b16(
    const float* __restrict__ A, const float* __restrict__ Bv, u16* __restrict__ Y, int M,
    const u16* __restrict__ gb, int ldg, int goff,
    const u16* __restrict__ ssb, int ldss, int shoff, int scoff,
    const float* __restrict__ gw, const float* __restrict__ bw)
{
    int row = (blockIdx.x << 2) + (threadIdx.x >> 6);
    if (row >= M) return;
    int lane = threadIdx.x & 63;
    const float* ar = A + (size_t)row * HID + lane * 4;
    const float* br = Bv + (size_t)row * HID + lane * 4;
    ushort4 gp = *(const ushort4*)(gb + (size_t)row * ldg + goff + lane * 4);
    float t0 = ar[0] + b2f(gp.x) * br[0];
    float t1 = ar[1] + b2f(gp.y) * br[1];
    float t2 = ar[2] + b2f(gp.z) * br[2];
    float t3 = ar[3] + b2f(gp.w) * br[3];
    float s = t0 + t1 + t2 + t3;
    float q = t0 * t0 + t1 * t1 + t2 * t2 + t3 * t3;
#pragma unroll
    for (int o = 32; o; o >>= 1) { s += __shfl_xor(s, o, 64); q += __shfl_xor(q, o, 64); }
    float m = s * (1.f / HID);
    float r = rsqrtf(q * (1.f / HID) - m * m + 1e-6f);
    float n0 = (t0 - m) * r, n1 = (t1 - m) * r, n2 = (t2 - m) * r, n3 = (t3 - m) * r;
    if (gw) {
        const float* g4 = gw + lane * 4;
        const float* b4 = bw + lane * 4;
        n0 = n0 * g4[0] + b4[0]; n1 = n1 * g4[1] + b4[1];
        n2 = n2 * g4[2] + b4[2]; n3 = n3 * g4[3] + b4[3];
    }
    const u16* sp = ssb + (size_t)row * ldss;
    ushort4 sh = *(const ushort4*)(sp + shoff + lane * 4);
    ushort4 sc = *(const ushort4*)(sp + scoff + lane * 4);
    ushort4 o;
    o.x = f2b(n0 * (1.f + b2f(sc.x)) + b2f(sh.x));
    o.y = f2b(n1 * (1.f + b2f(sc.y)) + b2f(sh.y));
    o.z = f2b(n2 * (1.f + b2f(sc.z)) + b2f(sh.z));
    o.w = f2b(n3 * (1.f + b2f(sc.w)) + b2f(sh.w));
    ((ushort4*)(Y + (size_t)row * HID))[lane] = o;
}

// ----- same, but Bv is bf16 --------------------------------------------------------------
__global__ __launch_bounds__(256) void k_ln_mod_resid_b16bv(
    const float* __restrict__ A, const u16* __restrict__ Bv, u16* __restrict__ Y, int M,
    const u16* __restrict__ gb, int ldg, int goff,
    const u16* __restrict__ ssb, int ldss, int shoff, int scoff)
{
    int row = (blockIdx.x << 2) + (threadIdx.x >> 6);
    if (row >= M) return;
    int lane = threadIdx.x & 63;
    const float* ar = A + (size_t)row * HID + lane * 4;
    ushort4 bv = ((const ushort4*)(Bv + (size_t)row * HID))[lane];
    ushort4 gp = *(const ushort4*)(gb + (size_t)row * ldg + goff + lane * 4);
    float t0 = ar[0] + b2f(gp.x) * b2f(bv.x);
    float t1 = ar[1] + b2f(gp.y) * b2f(bv.y);
    float t2 = ar[2] + b2f(gp.z) * b2f(bv.z);
    float t3 = ar[3] + b2f(gp.w) * b2f(bv.w);
    float s = t0 + t1 + t2 + t3;
    float q = t0 * t0 + t1 * t1 + t2 * t2 + t3 * t3;
#pragma unroll
    for (int o = 32; o; o >>= 1) { s += __shfl_xor(s, o, 64); q += __shfl_xor(q, o, 64); }
    float m = s * (1.f / HID);
    float r = rsqrtf(q * (1.f / HID) - m * m + 1e-6f);
    float n0 = (t0 - m) * r, n1 = (t1 - m) * r, n2 = (t2 - m) * r, n3 = (t3 - m) * r;
    const u16* sp = ssb + (size_t)row * ldss;
    ushort4 sh = *(const ushort4*)(sp + shoff + lane * 4);
    ushort4 sc = *(const ushort4*)(sp + scoff + lane * 4);
    ushort4 o;
    o.x = f2b(n0 * (1.f + b2f(sc.x)) + b2f(sh.x));
    o.y = f2b(n1 * (1.f + b2f(sc.y)) + b2f(sh.y));
    o.z = f2b(n2 * (1.f + b2f(sc.z)) + b2f(sh.z));
    o.w = f2b(n3 * (1.f + b2f(sc.w)) + b2f(sh.w));
    ((ushort4*)(Y + (size_t)row * HID))[lane] = o;
}

// ---------------- CSR build ------------------------------------------------------------
__global__ __launch_bounds__(256) void k_hist(
    const int* __restrict__ tgt, int* __restrict__ counts, int E)
{
    int i = blockIdx.x * 256 + threadIdx.x;
    if (i < E) atomicAdd(&counts[tgt[i]], 1);
}

__global__ __launch_bounds__(256) void k_scan(
    const int* __restrict__ counts, int* __restrict__ offsets, int Nn)
{
    __shared__ int part[256];
    __shared__ int pref[257];
    int t = threadIdx.x;
    int chunk = (Nn + 255) / 256;
    int lo = t * chunk, hi = imin(lo + chunk, Nn);
    int s = 0;
    for (int i = lo; i < hi; ++i) s += counts[i];
    part[t] = s;
    __syncthreads();
    if (t == 0) {
        int run = 0;
        for (int i = 0; i < 256; ++i) { pref[i] = run; run += part[i]; }
        pref[256] = run;
        offsets[Nn] = run;
    }
    __syncthreads();
    int run = pref[t];
    for (int i = lo; i < hi; ++i) { offsets[i] = run; run += counts[i]; }
}

__global__ __launch_bounds__(256) void k_scatter(
    const int* __restrict__ tgt, int* __restrict__ cursor,
    int* __restrict__ eidlist, int E)
{
    int i = blockIdx.x * 256 + threadIdx.x;
    if (i < E) {
        int pos = atomicAdd(&cursor[tgt[i]], 1);
        eidlist[pos] = i;
    }
}

__global__ __launch_bounds__(256) void k_amax_den(
    const float* __restrict__ alpha, const int* __restrict__ offsets,
    const int* __restrict__ eidlist, float* __restrict__ amaxF,
    float* __restrict__ invden, int NH8)
{
    int i = blockIdx.x * 256 + threadIdx.x;
    if (i >= NH8) return;
    int n = i >> 3, h = i & 7;
    int b = offsets[n], e = offsets[n + 1];
    float m = -1e30f;
    for (int k = b; k < e; ++k) m = fmaxf(m, alpha[(size_t)eidlist[k] * 8 + h]);
    float s = 0.f;
    for (int k = b; k < e; ++k) s += __expf(alpha[(size_t)eidlist[k] * 8 + h] - m);
    amaxF[i] = m;
    invden[i] = (s > 0.f) ? 1.f / s : 0.f;
}

__global__ __launch_bounds__(256) void k_norm(
    float* __restrict__ alpha, const float* __restrict__ amaxF,
    const float* __restrict__ invden, const int* __restrict__ tgt, int EH)
{
    int i = blockIdx.x * 256 + threadIdx.x;
    if (i >= EH) return;
    int e = i >> 3, h = i & 7;
    int g = tgt[e];
    alpha[i] = __expf(alpha[i] - amaxF[(size_t)g * 8 + h]) * invden[(size_t)g * 8 + h];
}

// message pass via CSR: hat[n,c] = V[n,c] * sum_{e in CSR[n]} e1[e,c]*w[e,h]
__global__ __launch_bounds__(256) void attn_msg_csr(
    const u16* __restrict__ qkv, const u16* __restrict__ e1b,
    const float* __restrict__ alpha, const int* __restrict__ offsets,
    const int* __restrict__ eidlist, float* __restrict__ hattn)
{
    int n = blockIdx.x;
    int c = threadIdx.x;
    int h = c >> 5;
    int b = offsets[n], e = offsets[n + 1];
    float acc = 0.f;
    for (int k = b; k < e; ++k) {
        int eid = eidlist[k];
        float w = alpha[(size_t)eid * 8 + h];
        acc += b2f(e1b[(size_t)eid * 256 + c]) * w;
    }
    hattn[(size_t)n * 256 + c] = b2f(qkv[(size_t)n * 768 + 512 + c]) * acc;
}

// ---------------------------------------------------------------------------------------
static inline void gemm(hipStream_t st, const u16* A, int lda, const u16* Bt, int ldb,
                        void* C, int ldc, int M, int N, int K,
                        const float* bias, int act, int obf16)
{
    dim3 g(N / 128, (M + 63) / 64);
    hipLaunchKernelGGL(gemm_mfma, g, dim3(256), 0, st, A, lda, Bt, ldb, C, ldc, M, N, K,
                       bias, act, obf16);
}

extern "C" void kernel_launch(void* const* d_in, const int* in_sizes, int n_in,
                              void* d_out, int out_size, void* d_ws, size_t ws_size,
                              hipStream_t stream)
{
    const int Nn = in_sizes[0];
    const int E = in_sizes[3] / HID;

    const float* x        = (const float*)d_in[1];
    const float* t_emb_h  = (const float*)d_in[2];
    const float* edge_attr= (const float*)d_in[3];
    const int*   eidx     = (const int*)d_in[4];
    const float* t_emb_e  = (const float*)d_in[5];
    const float* dist     = (const float*)d_in[6];
    const float* W_ee     = (const float*)d_in[7];
    const float* b_ee     = (const float*)d_in[8];
    const float* W_ad     = (const float*)d_in[9];
    const float* b_ad     = (const float*)d_in[10];
    const float* W_ade    = (const float*)d_in[11];
    const float* b_ade    = (const float*)d_in[12];
    const float* W_qkv    = (const float*)d_in[13];
    const float* W_e0     = (const float*)d_in[14];
    const float* W_e1     = (const float*)d_in[15];
    const float* W_n2e    = (const float*)d_in[16];
    const float* b_n2e    = (const float*)d_in[17];
    const float* g_ln     = (const float*)d_in[18];
    const float* b_ln     = (const float*)d_in[19];
    const float* W_f12    = (const float*)d_in[20];
    const float* W_fout   = (const float*)d_in[21];
    const float* W_fe12   = (const float*)d_in[22];
    const float* W_feout  = (const float*)d_in[23];

    const int* src = eidx;
    const int* tgt = eidx + E;

    float* outN = (float*)d_out;
    float* outE = (float*)d_out + (size_t)Nn * 256;

    // ---- persistent workspace ----
    char* W = (char*)d_ws;
    size_t off = 0;
    auto alloc = [&](size_t bytes) -> size_t {
        size_t o = off; off += (bytes + 255) & ~(size_t)255; return o;
    };
    float*    alpha = (float*)(W + alloc((size_t)E * 8 * 4));
    float*    amaxF = (float*)(W + alloc((size_t)Nn * 8 * 4));
    float*    invden= (float*)(W + alloc((size_t)Nn * 8 * 4));
    float*    hat   = (float*)(W + alloc((size_t)Nn * 256 * 4));
    int*      offs  = (int*)(W + alloc((size_t)(Nn + 1) * 4));
    int*      cursor= (int*)(W + alloc((size_t)Nn * 4));
    int*      eidl  = (int*)(W + alloc((size_t)E * 4));
    u16*      qkvb  = (u16*)(W + alloc((size_t)Nn * 768 * 2));
    u16*      sth   = (u16*)(W + alloc((size_t)Nn * 256 * 2));
    u16*      steb  = (u16*)(W + alloc((size_t)E * 256 * 2));    // silu(t_emb_e)
    u16*      eaeb  = (u16*)(W + alloc((size_t)E * 256 * 2));    // edge_attr_e (bf16)
    u16*      e1b   = (u16*)(W + alloc((size_t)E * 256 * 2));    // e_mod @ W_e1
    u16*      adnb  = (u16*)(W + alloc((size_t)Nn * 1536 * 2));
    u16*      xmb   = (u16*)(W + alloc((size_t)Nn * 256 * 2));
    u16*      h2nb  = (u16*)(W + alloc((size_t)Nn * 256 * 2));
    u16*      cnb   = (u16*)(W + alloc((size_t)Nn * 1024 * 2));
    // bf16 transposed weights (N x K)
    u16* weet   = (u16*)(W + alloc((size_t)256 * 384 * 2));
    u16* wadt   = (u16*)(W + alloc((size_t)1536 * 256 * 2));
    u16* wadet  = (u16*)(W + alloc((size_t)1536 * 256 * 2));
    u16* wqkvt  = (u16*)(W + alloc((size_t)768 * 256 * 2));
    u16* we01t  = (u16*)(W + alloc((size_t)512 * 256 * 2));
    u16* wn2et  = (u16*)(W + alloc((size_t)256 * 256 * 2));
    u16* wf12t  = (u16*)(W + alloc((size_t)2048 * 256 * 2));
    u16* wfoutt = (u16*)(W + alloc((size_t)256 * 1024 * 2));
    u16* wfe12t = (u16*)(W + alloc((size_t)2048 * 256 * 2));
    u16* wfeoutt= (u16*)(W + alloc((size_t)256 * 1024 * 2));

    char* pool = W + off;
    size_t poolB = (ws_size > off) ? (ws_size - off) : 0;
    auto chunkRowsB = [&](size_t bytesPerRow, int total) -> int {
        long c = (long)(poolB / bytesPerRow);
        c = (c / 256) * 256;
        if (c < 256) c = 256;
        if (c > total) c = (long)total;
        return (int)c;
    };

    // ---- CSR build by tgt ----
    hipMemsetAsync(cursor, 0, (size_t)Nn * 4, stream);
    hipLaunchKernelGGL(k_hist, dim3((E + 255) / 256), dim3(256), 0, stream, tgt, cursor, E);
    hipLaunchKernelGGL(k_scan, dim3(1), dim3(256), 0, stream, cursor, offs, Nn);
    hipMemcpyAsync(cursor, offs, (size_t)Nn * 4, hipMemcpyDeviceToDevice, stream);
    hipLaunchKernelGGL(k_scatter, dim3((E + 255) / 256), dim3(256), 0, stream,
                       tgt, cursor, eidl, E);

    // ---- weight conversion ----
    {
        struct WC { const float* w; u16* wt; int K, N; } wl[] = {
            { W_ee,    weet,   384, 256 },
            { W_ad,    wadt,   256, 1536 },
            { W_ade,   wadet,  256, 1536 },
            { W_qkv,   wqkvt,  256, 768 },
            { W_e0,    we01t,  256, 256 },
            { W_e1,    we01t + 256 * 256, 256, 256 },
            { W_n2e,   wn2et,  256, 256 },
            { W_f12,   wf12t,  256, 2048 },
            { W_fout,  wfoutt, 1024, 256 },
            { W_fe12,  wfe12t, 256, 2048 },
            { W_feout, wfeoutt,1024, 256 },
        };
        for (auto& e : wl) {
            int cnt = e.K * e.N;
            hipLaunchKernelGGL(k_wconv, dim3((cnt + 255) / 256), dim3(256), 0, stream,
                               e.w, e.wt, e.K, e.N);
        }
    }

    // silu conversions (persistent)
    hipLaunchKernelGGL(k_silu_b16, dim3((unsigned)(((long long)Nn * 64 + 255) / 256)), dim3(256),
                       0, stream, t_emb_h, sth, (long long)Nn * 64);
    hipLaunchKernelGGL(k_silu_b16, dim3((unsigned)(((long long)E * 64 + 255) / 256)), dim3(256),
                       0, stream, t_emb_e, steb, (long long)E * 64);

    // ---- phase 1: node pre ----
    gemm(stream, sth, 256, wadt, 256, adnb, 1536, Nn, 1536, 256, b_ad, 0, 1);
    hipLaunchKernelGGL(k_ln_mod_b16, dim3((Nn + 3) / 4), dim3(256), 0, stream,
                       x, xmb, Nn, adnb, 1536, 0, 256);
    gemm(stream, xmb, 256, wqkvt, 256, qkvb, 768, Nn, 768, 256, nullptr, 0, 1);

    // ---- phase 2: edge pre ----
    {
        int C = chunkRowsB(1024 + 512, E);
        char* p = pool;
        u16* emsb = (u16*)p; p += (size_t)C * 1024;   // adaln_e[:,0:512) (bf16)
        u16* emod = (u16*)p;                          // C x 256 bf16
        for (int s = 0; s < E; s += C) {
            int cc = (E - s < C) ? (E - s) : C;
            hipLaunchKernelGGL(gemm_cat, dim3(2, (cc + 63) / 64), dim3(256), 0, stream,
                               edge_attr + (size_t)s * 256, dist + (size_t)s * 128,
                               weet, eaeb + (size_t)s * 256, cc, b_ee);
            gemm(stream, steb + (size_t)s * 256, 256, wadet, 256, emsb, 512, cc, 512, 256,
                 b_ade, 0, 1);
            hipLaunchKernelGGL(k_ln_mod_b16src, dim3((cc + 3) / 4), dim3(256), 0, stream,
                               eaeb + (size_t)s * 256, emod, cc, emsb, 512, 0, 256);
            hipLaunchKernelGGL(gemm_e01, dim3(4, (cc + 63) / 64), dim3(256), 0, stream,
                               emod, we01t, e1b + (size_t)s * 256, cc,
                               qkvb, src + s, tgt + s, alpha + (size_t)s * 8);
        }
    }

    // ---- phase 3: softmax stats + normalize ----
    hipLaunchKernelGGL(k_amax_den, dim3((Nn * 8 + 255) / 256), dim3(256), 0, stream,
                       alpha, offs, eidl, amaxF, invden, Nn * 8);
    hipLaunchKernelGGL(k_norm, dim3((E * 8 + 255) / 256), dim3(256), 0, stream,
                       alpha, amaxF, invden, tgt, E * 8);

    // ---- phase 4: message pass via CSR ----
    hipLaunchKernelGGL(attn_msg_csr, dim3(Nn), dim3(256), 0, stream,
                       qkvb, e1b, alpha, offs, eidl, hat);

    // ---- phase 5: node finish ----
    hipLaunchKernelGGL(k_ln_mod_resid_b16, dim3((Nn + 3) / 4), dim3(256), 0, stream,
                       x, hat, h2nb, Nn, adnb, 1536, 512, adnb, 1536, 768, 1024, g_ln, b_ln);
    hipLaunchKernelGGL(gemm_ffn12, dim3(16, (Nn + 63) / 64), dim3(256), 0, stream,
                       h2nb, wf12t, cnb, Nn);
    hipLaunchKernelGGL(gemm_out_final, dim3(2, (Nn + 63) / 64), dim3(256), 0, stream,
                       cnb, wfoutt, (const u16*)nullptr, h2nb, adnb, 1536, 1280, outN, Nn);

    // ---- phase 6: edge finish ----
    {
        int C = chunkRowsB(2048 + 512 + 512 + 2048, E);
        char* p = pool;
        u16*   em2b = (u16*)p;  p += (size_t)C * 2048;   // adaln_e[:,512:1536)
        u16*   hep  = (u16*)p;  p += (size_t)C * 512;    // bf16
        u16*   h2e  = (u16*)p;  p += (size_t)C * 512;
        u16*   cne  = (u16*)p;                            // swiglu out C x 1024
        for (int s = 0; s < E; s += C) {
            int cc = (E - s < C) ? (E - s) : C;
            hipLaunchKernelGGL(gemm_gsum, dim3(2, (cc + 63) / 64), dim3(256), 0, stream,
                               hat, src + s, tgt + s, wn2et, hep, cc, b_n2e);
            gemm(stream, steb + (size_t)s * 256, 256, wadet + 512 * 256, 256, em2b, 1024,
                 cc, 1024, 256, b_ade + 512, 0, 1);
            hipLaunchKernelGGL(k_ln_mod_resid_b16bv, dim3((cc + 3) / 4), dim3(256), 0, stream,
                               edge_attr + (size_t)s * 256, hep, h2e, cc,
                               em2b, 1024, 0, em2b, 1024, 256, 512);
            hipLaunchKernelGGL(gemm_ffn12, dim3(16, (cc + 63) / 64), dim3(256), 0, stream,
                               h2e, wfe12t, cne, cc);
            hipLaunchKernelGGL(gemm_out_final, dim3(2, (cc + 63) / 64), dim3(256), 0, stream,
                               cne, wfeoutt, eaeb + (size_t)s * 256, h2e,
                               em2b, 1024, 768, outE + (size_t)s * 256, cc);
        }
    }
    (void)n_in; (void)out_size;
}

// Round 20
// 1838.346 us; speedup vs baseline: 1.2026x; 1.0310x over previous
//
#include <hip/hip_runtime.h>

#define HID 256

typedef unsigned short u16;
typedef __attribute__((ext_vector_type(8))) short bf16x8;
typedef __attribute__((ext_vector_type(4))) float f32x4;

__device__ __forceinline__ float siluf(float x) { return x / (1.f + __expf(-x)); }
// tanh-approx gelu via sigmoid identity: 0.5x(1+tanh(z)) == x*sigmoid(2z)
__device__ __forceinline__ float geluf(float x) {
    return x / (1.f + __expf(-(1.59576912f * x + 0.07135481f * x * x * x)));
}
__device__ __forceinline__ u16 f2b(float x) {
    unsigned u = __float_as_uint(x);
    unsigned r = u + 0x7FFFu + ((u >> 16) & 1u);
    return (u16)(r >> 16);
}
__device__ __forceinline__ float b2f(u16 h) {
    return __uint_as_float(((unsigned)h) << 16);
}
__device__ __forceinline__ void gload16(const u16* g, u16* l) {
    __builtin_amdgcn_global_load_lds(
        (const __attribute__((address_space(1))) unsigned int*)g,
        (__attribute__((address_space(3))) unsigned int*)l, 16, 0, 0);
}
__device__ __forceinline__ int imin(int a, int b) { return a < b ? a : b; }

union B16x8 { u16 u[8]; uint4 q; };

// ---------------- bf16 MFMA GEMM: C = act(A @ Bt^T + bias) ------------------------------
// A: M x K bf16 (lda). Bt: N x K bf16 (ldb). 64x128 tile, BK=32, 4 waves 2x2 of 32x64.
// act: 1=silu, 2=gelu. N%128==0, K%32==0.
__global__ __launch_bounds__(256) void gemm_mfma(
    const u16* __restrict__ A, int lda,
    const u16* __restrict__ Bt, int ldb,
    void* __restrict__ Cv, int ldc,
    int M, int N, int K,
    const float* __restrict__ bias, int act, int obf16)
{
    __shared__ u16 lds[8192];

    const int tid  = threadIdx.x;
    const int lane = tid & 63;
    const int wave = tid >> 6;
    const int row0 = blockIdx.y * 64;
    const int col0 = blockIdx.x * 128;
    const int wm   = (wave >> 1) * 32;
    const int wn   = (wave & 1) * 64;

    f32x4 acc[2][4];
#pragma unroll
    for (int i = 0; i < 2; ++i)
#pragma unroll
        for (int j = 0; j < 4; ++j) acc[i][j] = (f32x4)0.0f;

    const int kc = (lane & 3) * 8;
    const int rr  = wave * 16 + (lane >> 2);
    const int rb1 = (wave + 4) * 16 + (lane >> 2);
    const u16* pa  = A + (size_t)imin(row0 + rr, M - 1) * lda + kc;
    const u16* pb0 = Bt + (size_t)(col0 + rr) * ldb + kc;
    const u16* pb1 = Bt + (size_t)(col0 + rb1) * ldb + kc;
    u16* la  = &lds[wave * 512];
    u16* lb0 = &lds[2048 + wave * 512];
    u16* lb1 = &lds[2048 + (wave + 4) * 512];

    const int kb = (lane >> 4) * 8;
    const int fr = lane & 15;

    for (int k0 = 0; k0 < K; k0 += 32) {
        gload16(pa + k0, la);
        gload16(pb0 + k0, lb0);
        gload16(pb1 + k0, lb1);
        __syncthreads();

        bf16x8 af[2], bfm[4];
#pragma unroll
        for (int i = 0; i < 2; ++i)
            af[i] = *(const bf16x8*)&lds[(wm + i * 16 + fr) * 32 + kb];
#pragma unroll
        for (int j = 0; j < 4; ++j)
            bfm[j] = *(const bf16x8*)&lds[2048 + (wn + j * 16 + fr) * 32 + kb];
#pragma unroll
        for (int i = 0; i < 2; ++i)
#pragma unroll
            for (int j = 0; j < 4; ++j)
                acc[i][j] = __builtin_amdgcn_mfma_f32_16x16x32_bf16(af[i], bfm[j], acc[i][j], 0, 0, 0);
        __syncthreads();
    }

    const int qr = (lane >> 4) * 4;
    if (obf16) {
#pragma unroll
        for (int i = 0; i < 2; ++i)
#pragma unroll
            for (int r = 0; r < 4; ++r)
#pragma unroll
                for (int j = 0; j < 4; ++j) {
                    int lcol = wn + j * 16 + fr;
                    int gcol = col0 + lcol;
                    float v = acc[i][j][r];
                    if (bias) v += bias[gcol];
                    if (act == 2) v = geluf(v);
                    else if (act == 1) v = siluf(v);
                    lds[(wm + i * 16 + qr + r) * 128 + lcol] = f2b(v);
                }
        __syncthreads();
        int row = tid >> 2, cc0 = (tid & 3) * 32;
        int grow = row0 + row;
        if (grow < M) {
            uint4* dst = (uint4*)((u16*)Cv + (size_t)grow * ldc + col0 + cc0);
            const uint4* sp = (const uint4*)&lds[row * 128 + cc0];
            dst[0] = sp[0]; dst[1] = sp[1]; dst[2] = sp[2]; dst[3] = sp[3];
        }
    } else {
        float* Cf = (float*)Cv;
#pragma unroll
        for (int i = 0; i < 2; ++i)
#pragma unroll
            for (int r = 0; r < 4; ++r) {
                int grow = row0 + wm + i * 16 + qr + r;
                if (grow >= M) continue;
#pragma unroll
                for (int j = 0; j < 4; ++j) {
                    int gcol = col0 + wn + j * 16 + fr;
                    float v = acc[i][j][r];
                    if (bias) v += bias[gcol];
                    if (act == 2) v = geluf(v);
                    else if (act == 1) v = siluf(v);
                    Cf[(size_t)grow * ldc + gcol] = v;
                }
            }
    }
}

// ------- gemm_siluA: C(bf16) = silu(A_fp32) @ Bt^T + bias -------------------------------
// A: M x 256 fp32 (reg-staged with in-register silu+f2b). K=256 fixed.
// grid (N/128, ceil(M/64)). C ldc param, bf16 repack store.
__global__ __launch_bounds__(256) void gemm_siluA(
    const float* __restrict__ A, const u16* __restrict__ Bt,
    u16* __restrict__ C, int ldc, int M, const float* __restrict__ bias)
{
    __shared__ u16 lds[8192];

    const int tid  = threadIdx.x;
    const int lane = tid & 63;
    const int wave = tid >> 6;
    const int row0 = blockIdx.y * 64;
    const int col0 = blockIdx.x * 128;
    const int wm   = (wave >> 1) * 32;
    const int wn   = (wave & 1) * 64;

    f32x4 acc[2][4];
#pragma unroll
    for (int i = 0; i < 2; ++i)
#pragma unroll
        for (int j = 0; j < 4; ++j) acc[i][j] = (f32x4)0.0f;

    const int kc = (lane & 3) * 8;
    const int rr  = wave * 16 + (lane >> 2);
    const int rb1 = (wave + 4) * 16 + (lane >> 2);
    const int gr  = imin(row0 + rr, M - 1);
    const u16* pb0 = Bt + (size_t)(col0 + rr) * 256 + kc;
    const u16* pb1 = Bt + (size_t)(col0 + rb1) * 256 + kc;
    u16* lb0 = &lds[2048 + wave * 512];
    u16* lb1 = &lds[2048 + (wave + 4) * 512];
    u16* laD = &lds[wave * 512 + (lane & 63) * 8];   // == row-major [64][32] slot

    const int kb = (lane >> 4) * 8;
    const int fr = lane & 15;

    for (int k0 = 0; k0 < 256; k0 += 32) {
        const float* sp = A + (size_t)gr * 256 + k0 + kc;
        float4 v0 = *(const float4*)sp;
        float4 v1 = *(const float4*)(sp + 4);
        gload16(pb0 + k0, lb0);
        gload16(pb1 + k0, lb1);
        B16x8 t;
        t.u[0] = f2b(siluf(v0.x)); t.u[1] = f2b(siluf(v0.y));
        t.u[2] = f2b(siluf(v0.z)); t.u[3] = f2b(siluf(v0.w));
        t.u[4] = f2b(siluf(v1.x)); t.u[5] = f2b(siluf(v1.y));
        t.u[6] = f2b(siluf(v1.z)); t.u[7] = f2b(siluf(v1.w));
        *(uint4*)laD = t.q;
        __syncthreads();

        bf16x8 af[2], bfm[4];
#pragma unroll
        for (int i = 0; i < 2; ++i)
            af[i] = *(const bf16x8*)&lds[(wm + i * 16 + fr) * 32 + kb];
#pragma unroll
        for (int j = 0; j < 4; ++j)
            bfm[j] = *(const bf16x8*)&lds[2048 + (wn + j * 16 + fr) * 32 + kb];
#pragma unroll
        for (int i = 0; i < 2; ++i)
#pragma unroll
            for (int j = 0; j < 4; ++j)
                acc[i][j] = __builtin_amdgcn_mfma_f32_16x16x32_bf16(af[i], bfm[j], acc[i][j], 0, 0, 0);
        __syncthreads();
    }

    const int qr = (lane >> 4) * 4;
#pragma unroll
    for (int i = 0; i < 2; ++i)
#pragma unroll
        for (int r = 0; r < 4; ++r)
#pragma unroll
            for (int j = 0; j < 4; ++j) {
                int lcol = wn + j * 16 + fr;
                float v = acc[i][j][r] + bias[col0 + lcol];
                lds[(wm + i * 16 + qr + r) * 128 + lcol] = f2b(v);
            }
    __syncthreads();
    int row = tid >> 2, cc0 = (tid & 3) * 32;
    int grow = row0 + row;
    if (grow < M) {
        uint4* dst = (uint4*)(C + (size_t)grow * ldc + col0 + cc0);
        const uint4* sp = (const uint4*)&lds[row * 128 + cc0];
        dst[0] = sp[0]; dst[1] = sp[1]; dst[2] = sp[2]; dst[3] = sp[3];
    }
}

// ------- gemm_e01: fused [gelu(emod@We0)->alpha | emod@We1->e1b] ------------------------
// A: emod M x 256 bf16. Bt: we01t 512 x 256. grid (4, ceil(M/64)).
// bx<2: gelu cols (heads bx*4..bx*4+3) -> compute alpha[e,h] in-epilogue, NO global store.
// bx>=2: plain -> store to e1b (M x 256).
__global__ __launch_bounds__(256) void gemm_e01(
    const u16* __restrict__ A, const u16* __restrict__ Bt,
    u16* __restrict__ e1b, int M,
    const u16* __restrict__ qkv, const int* __restrict__ srcI, const int* __restrict__ tgtI,
    float* __restrict__ alpha)
{
    __shared__ u16 lds[8192];

    const int tid  = threadIdx.x;
    const int lane = tid & 63;
    const int wave = tid >> 6;
    const int row0 = blockIdx.y * 64;
    const int bx   = blockIdx.x;
    const int col0 = bx * 128;
    const int wm   = (wave >> 1) * 32;
    const int wn   = (wave & 1) * 64;

    f32x4 acc[2][4];
#pragma unroll
    for (int i = 0; i < 2; ++i)
#pragma unroll
        for (int j = 0; j < 4; ++j) acc[i][j] = (f32x4)0.0f;

    const int kc = (lane & 3) * 8;
    const int rr  = wave * 16 + (lane >> 2);
    const int rb1 = (wave + 4) * 16 + (lane >> 2);
    const u16* pa  = A + (size_t)imin(row0 + rr, M - 1) * 256 + kc;
    const u16* pb0 = Bt + (size_t)(col0 + rr) * 256 + kc;
    const u16* pb1 = Bt + (size_t)(col0 + rb1) * 256 + kc;
    u16* la  = &lds[wave * 512];
    u16* lb0 = &lds[2048 + wave * 512];
    u16* lb1 = &lds[2048 + (wave + 4) * 512];

    const int kb = (lane >> 4) * 8;
    const int fr = lane & 15;

    for (int k0 = 0; k0 < 256; k0 += 32) {
        gload16(pa + k0, la);
        gload16(pb0 + k0, lb0);
        gload16(pb1 + k0, lb1);
        __syncthreads();

        bf16x8 af[2], bfm[4];
#pragma unroll
        for (int i = 0; i < 2; ++i)
            af[i] = *(const bf16x8*)&lds[(wm + i * 16 + fr) * 32 + kb];
#pragma unroll
        for (int j = 0; j < 4; ++j)
            bfm[j] = *(const bf16x8*)&lds[2048 + (wn + j * 16 + fr) * 32 + kb];
#pragma unroll
        for (int i = 0; i < 2; ++i)
#pragma unroll
            for (int j = 0; j < 4; ++j)
                acc[i][j] = __builtin_amdgcn_mfma_f32_16x16x32_bf16(af[i], bfm[j], acc[i][j], 0, 0, 0);
        __syncthreads();
    }

    const int qr = (lane >> 4) * 4;
    const bool isE0 = (bx < 2);
#pragma unroll
    for (int i = 0; i < 2; ++i)
#pragma unroll
        for (int r = 0; r < 4; ++r)
#pragma unroll
            for (int j = 0; j < 4; ++j) {
                int lcol = wn + j * 16 + fr;
                float v = acc[i][j][r];
                if (isE0) v = geluf(v);
                lds[(wm + i * 16 + qr + r) * 128 + lcol] = f2b(v);
            }
    __syncthreads();
    int row = tid >> 2, cc0 = (tid & 3) * 32;
    int grow = row0 + row;
    if (grow < M) {
        if (isE0) {
            int head = bx * 4 + (tid & 3);
            const u16* qv = qkv + (size_t)srcI[grow] * 768 + head * 32;
            const u16* kv = qkv + (size_t)tgtI[grow] * 768 + 256 + head * 32;
            const u16* gv = &lds[row * 128 + cc0];
            float s = 0.f;
#pragma unroll
            for (int c = 0; c < 32; ++c)
                s += b2f(gv[c]) * b2f(qv[c]) * b2f(kv[c]);
            alpha[(size_t)grow * 8 + head] = s * 0.17677669529663687f;
        } else {
            uint4* dst = (uint4*)(e1b + (size_t)grow * 256 + (col0 - 256) + cc0);
            const uint4* sp = (const uint4*)&lds[row * 128 + cc0];
            dst[0] = sp[0]; dst[1] = sp[1]; dst[2] = sp[2]; dst[3] = sp[3];
        }
    }
}

// ------- gemm_cat: C(bf16) = [A1(fp32,256) | A2(fp32,128)] @ Bt^T + bias ----------------
__global__ __launch_bounds__(256) void gemm_cat(
    const float* __restrict__ A1, const float* __restrict__ A2,
    const u16* __restrict__ Bt,
    u16* __restrict__ C, int M, const float* __restrict__ bias)
{
    __shared__ u16 lds[8192];

    const int tid  = threadIdx.x;
    const int lane = tid & 63;
    const int wave = tid >> 6;
    const int row0 = blockIdx.y * 64;
    const int col0 = blockIdx.x * 128;
    const int wm   = (wave >> 1) * 32;
    const int wn   = (wave & 1) * 64;

    f32x4 acc[2][4];
#pragma unroll
    for (int i = 0; i < 2; ++i)
#pragma unroll
        for (int j = 0; j < 4; ++j) acc[i][j] = (f32x4)0.0f;

    const int kc = (lane & 3) * 8;
    const int rr  = wave * 16 + (lane >> 2);
    const int rb1 = (wave + 4) * 16 + (lane >> 2);
    const int gr  = imin(row0 + rr, M - 1);
    const u16* pb0 = Bt + (size_t)(col0 + rr) * 384 + kc;
    const u16* pb1 = Bt + (size_t)(col0 + rb1) * 384 + kc;
    u16* lb0 = &lds[2048 + wave * 512];
    u16* lb1 = &lds[2048 + (wave + 4) * 512];
    u16* laD = &lds[wave * 512 + (lane & 63) * 8];

    const int kb = (lane >> 4) * 8;
    const int fr = lane & 15;

    for (int k0 = 0; k0 < 384; k0 += 32) {
        int kk = k0 + kc;
        const float* sp = (kk < 256) ? (A1 + (size_t)gr * 256 + kk)
                                     : (A2 + (size_t)gr * 128 + (kk - 256));
        float4 v0 = *(const float4*)sp;
        float4 v1 = *(const float4*)(sp + 4);
        gload16(pb0 + k0, lb0);
        gload16(pb1 + k0, lb1);
        B16x8 t;
        t.u[0] = f2b(v0.x); t.u[1] = f2b(v0.y); t.u[2] = f2b(v0.z); t.u[3] = f2b(v0.w);
        t.u[4] = f2b(v1.x); t.u[5] = f2b(v1.y); t.u[6] = f2b(v1.z); t.u[7] = f2b(v1.w);
        *(uint4*)laD = t.q;
        __syncthreads();

        bf16x8 af[2], bfm[4];
#pragma unroll
        for (int i = 0; i < 2; ++i)
            af[i] = *(const bf16x8*)&lds[(wm + i * 16 + fr) * 32 + kb];
#pragma unroll
        for (int j = 0; j < 4; ++j)
            bfm[j] = *(const bf16x8*)&lds[2048 + (wn + j * 16 + fr) * 32 + kb];
#pragma unroll
        for (int i = 0; i < 2; ++i)
#pragma unroll
            for (int j = 0; j < 4; ++j)
                acc[i][j] = __builtin_amdgcn_mfma_f32_16x16x32_bf16(af[i], bfm[j], acc[i][j], 0, 0, 0);
        __syncthreads();
    }

    const int qr = (lane >> 4) * 4;
#pragma unroll
    for (int i = 0; i < 2; ++i)
#pragma unroll
        for (int r = 0; r < 4; ++r)
#pragma unroll
            for (int j = 0; j < 4; ++j) {
                int lcol = wn + j * 16 + fr;
                float v = acc[i][j][r] + bias[col0 + lcol];
                lds[(wm + i * 16 + qr + r) * 128 + lcol] = f2b(v);
            }
    __syncthreads();
    int row = tid >> 2, cc0 = (tid & 3) * 32;
    int grow = row0 + row;
    if (grow < M) {
        uint4* dst = (uint4*)(C + (size_t)grow * 256 + col0 + cc0);
        const uint4* sp = (const uint4*)&lds[row * 128 + cc0];
        dst[0] = sp[0]; dst[1] = sp[1]; dst[2] = sp[2]; dst[3] = sp[3];
    }
}

// ------- gemm_gsum: C(bf16) = (hat[src]+hat[tgt]) @ Wn2e^T + b_n2e ----------------------
__global__ __launch_bounds__(256) void gemm_gsum(
    const float* __restrict__ hat, const int* __restrict__ srcI, const int* __restrict__ tgtI,
    const u16* __restrict__ Bt,
    u16* __restrict__ C, int M, const float* __restrict__ bias)
{
    __shared__ u16 lds[8192];

    const int tid  = threadIdx.x;
    const int lane = tid & 63;
    const int wave = tid >> 6;
    const int row0 = blockIdx.y * 64;
    const int col0 = blockIdx.x * 128;
    const int wm   = (wave >> 1) * 32;
    const int wn   = (wave & 1) * 64;

    f32x4 acc[2][4];
#pragma unroll
    for (int i = 0; i < 2; ++i)
#pragma unroll
        for (int j = 0; j < 4; ++j) acc[i][j] = (f32x4)0.0f;

    const int kc = (lane & 3) * 8;
    const int rr  = wave * 16 + (lane >> 2);
    const int rb1 = (wave + 4) * 16 + (lane >> 2);
    const int gr  = imin(row0 + rr, M - 1);
    const float* ps = hat + (size_t)srcI[gr] * 256 + kc;
    const float* pt = hat + (size_t)tgtI[gr] * 256 + kc;
    const u16* pb0 = Bt + (size_t)(col0 + rr) * 256 + kc;
    const u16* pb1 = Bt + (size_t)(col0 + rb1) * 256 + kc;
    u16* lb0 = &lds[2048 + wave * 512];
    u16* lb1 = &lds[2048 + (wave + 4) * 512];
    u16* laD = &lds[wave * 512 + (lane & 63) * 8];

    const int kb = (lane >> 4) * 8;
    const int fr = lane & 15;

    for (int k0 = 0; k0 < 256; k0 += 32) {
        float4 a0 = *(const float4*)(ps + k0);
        float4 a1 = *(const float4*)(ps + k0 + 4);
        float4 b0 = *(const float4*)(pt + k0);
        float4 b1 = *(const float4*)(pt + k0 + 4);
        gload16(pb0 + k0, lb0);
        gload16(pb1 + k0, lb1);
        B16x8 t;
        t.u[0] = f2b(a0.x + b0.x); t.u[1] = f2b(a0.y + b0.y);
        t.u[2] = f2b(a0.z + b0.z); t.u[3] = f2b(a0.w + b0.w);
        t.u[4] = f2b(a1.x + b1.x); t.u[5] = f2b(a1.y + b1.y);
        t.u[6] = f2b(a1.z + b1.z); t.u[7] = f2b(a1.w + b1.w);
        *(uint4*)laD = t.q;
        __syncthreads();

        bf16x8 af[2], bfm[4];
#pragma unroll
        for (int i = 0; i < 2; ++i)
            af[i] = *(const bf16x8*)&lds[(wm + i * 16 + fr) * 32 + kb];
#pragma unroll
        for (int j = 0; j < 4; ++j)
            bfm[j] = *(const bf16x8*)&lds[2048 + (wn + j * 16 + fr) * 32 + kb];
#pragma unroll
        for (int i = 0; i < 2; ++i)
#pragma unroll
            for (int j = 0; j < 4; ++j)
                acc[i][j] = __builtin_amdgcn_mfma_f32_16x16x32_bf16(af[i], bfm[j], acc[i][j], 0, 0, 0);
        __syncthreads();
    }

    const int qr = (lane >> 4) * 4;
#pragma unroll
    for (int i = 0; i < 2; ++i)
#pragma unroll
        for (int r = 0; r < 4; ++r)
#pragma unroll
            for (int j = 0; j < 4; ++j) {
                int lcol = wn + j * 16 + fr;
                float v = acc[i][j][r] + bias[col0 + lcol];
                lds[(wm + i * 16 + qr + r) * 128 + lcol] = f2b(v);
            }
    __syncthreads();
    int row = tid >> 2, cc0 = (tid & 3) * 32;
    int grow = row0 + row;
    if (grow < M) {
        uint4* dst = (uint4*)(C + (size_t)grow * 256 + col0 + cc0);
        const uint4* sp = (const uint4*)&lds[row * 128 + cc0];
        dst[0] = sp[0]; dst[1] = sp[1]; dst[2] = sp[2]; dst[3] = sp[3];
    }
}

// ---------------- fused FFN12 + swiglu ---------------------------------------------------
__global__ __launch_bounds__(256) void gemm_ffn12(
    const u16* __restrict__ A, const u16* __restrict__ Wt,
    u16* __restrict__ C, int M)
{
    __shared__ u16 sm[6144];
    u16* lsA = sm;
    u16* lsB1 = sm + 2048;
    u16* lsB2 = sm + 4096;

    const int tid  = threadIdx.x;
    const int lane = tid & 63;
    const int wave = tid >> 6;
    const int row0 = blockIdx.y * 64;
    const int col0 = blockIdx.x * 64;
    const int wm   = (wave >> 1) * 32;
    const int wn   = (wave & 1) * 32;

    f32x4 accA[2][2], accB[2][2];
#pragma unroll
    for (int i = 0; i < 2; ++i)
#pragma unroll
        for (int j = 0; j < 2; ++j) { accA[i][j] = (f32x4)0.0f; accB[i][j] = (f32x4)0.0f; }

    const int kc = (lane & 3) * 8;
    const int rr = wave * 16 + (lane >> 2);
    const u16* pa  = A + (size_t)imin(row0 + rr, M - 1) * 256 + kc;
    const u16* pb1 = Wt + (size_t)(col0 + rr) * 256 + kc;
    const u16* pb2 = Wt + (size_t)(1024 + col0 + rr) * 256 + kc;
    u16* la  = &lsA[wave * 512];
    u16* lb1 = &lsB1[wave * 512];
    u16* lb2 = &lsB2[wave * 512];

    const int kb = (lane >> 4) * 8;
    const int fr = lane & 15;

#pragma unroll 1
    for (int k0 = 0; k0 < 256; k0 += 32) {
        gload16(pa + k0, la);
        gload16(pb1 + k0, lb1);
        gload16(pb2 + k0, lb2);
        __syncthreads();

        bf16x8 af[2], b1f[2], b2f_[2];
#pragma unroll
        for (int i = 0; i < 2; ++i)
            af[i] = *(const bf16x8*)&lsA[(wm + i * 16 + fr) * 32 + kb];
#pragma unroll
        for (int j = 0; j < 2; ++j) {
            b1f[j] = *(const bf16x8*)&lsB1[(wn + j * 16 + fr) * 32 + kb];
            b2f_[j] = *(const bf16x8*)&lsB2[(wn + j * 16 + fr) * 32 + kb];
        }
#pragma unroll
        for (int i = 0; i < 2; ++i)
#pragma unroll
            for (int j = 0; j < 2; ++j) {
                accA[i][j] = __builtin_amdgcn_mfma_f32_16x16x32_bf16(af[i], b1f[j], accA[i][j], 0, 0, 0);
                accB[i][j] = __builtin_amdgcn_mfma_f32_16x16x32_bf16(af[i], b2f_[j], accB[i][j], 0, 0, 0);
            }
        __syncthreads();
    }

    const int qr = (lane >> 4) * 4;
#pragma unroll
    for (int i = 0; i < 2; ++i)
#pragma unroll
        for (int r = 0; r < 4; ++r)
#pragma unroll
            for (int j = 0; j < 2; ++j) {
                float a = accA[i][j][r], b = accB[i][j][r];
                sm[(wm + i * 16 + qr + r) * 64 + wn + j * 16 + fr] = f2b(siluf(a) * b);
            }
    __syncthreads();
    int row = tid >> 2, cc0 = (tid & 3) * 16;
    int grow = row0 + row;
    if (grow < M) {
        uint4* dst = (uint4*)(C + (size_t)grow * 1024 + col0 + cc0);
        const uint4* sp = (const uint4*)&sm[row * 64 + cc0];
        dst[0] = sp[0]; dst[1] = sp[1];
    }
}

// ---------------- fused FFN-out + final: out = [eae(bf16) +] h2 + gate*(A@Wout) --------
__global__ __launch_bounds__(256) void gemm_out_final(
    const u16* __restrict__ A, const u16* __restrict__ Bt,
    const u16* __restrict__ eae, const u16* __restrict__ h2,
    const u16* __restrict__ gate, int ldg, int goff,
    float* __restrict__ out, int M)
{
    __shared__ u16 lds[6144];

    const int tid  = threadIdx.x;
    const int lane = tid & 63;
    const int wave = tid >> 6;
    const int row0 = blockIdx.y * 64;
    const int col0 = blockIdx.x * 128;
    const int wm   = (wave >> 1) * 32;
    const int wn   = (wave & 1) * 64;

    f32x4 acc[2][4];
#pragma unroll
    for (int i = 0; i < 2; ++i)
#pragma unroll
        for (int j = 0; j < 4; ++j) acc[i][j] = (f32x4)0.0f;

    const int kc = (lane & 3) * 8;
    const int rr = wave * 16 + (lane >> 2);
    const int rb1 = (wave + 4) * 16 + (lane >> 2);
    const u16* pa  = A + (size_t)imin(row0 + rr, M - 1) * 1024 + kc;
    const u16* pb0 = Bt + (size_t)(col0 + rr) * 1024 + kc;
    const u16* pb1 = Bt + (size_t)(col0 + rb1) * 1024 + kc;
    u16* la  = &lds[wave * 512];
    u16* lb0 = &lds[2048 + wave * 512];
    u16* lb1 = &lds[2048 + (wave + 4) * 512];

    const int kb = (lane >> 4) * 8;
    const int fr = lane & 15;

#pragma unroll 1
    for (int k0 = 0; k0 < 1024; k0 += 32) {
        gload16(pa + k0, la);
        gload16(pb0 + k0, lb0);
        gload16(pb1 + k0, lb1);
        __syncthreads();

        bf16x8 af[2], bfm[4];
#pragma unroll
        for (int i = 0; i < 2; ++i)
            af[i] = *(const bf16x8*)&lds[(wm + i * 16 + fr) * 32 + kb];
#pragma unroll
        for (int j = 0; j < 4; ++j)
            bfm[j] = *(const bf16x8*)&lds[2048 + (wn + j * 16 + fr) * 32 + kb];
#pragma unroll
        for (int i = 0; i < 2; ++i)
#pragma unroll
            for (int j = 0; j < 4; ++j)
                acc[i][j] = __builtin_amdgcn_mfma_f32_16x16x32_bf16(af[i], bfm[j], acc[i][j], 0, 0, 0);
        __syncthreads();
    }

    const int qr = (lane >> 4) * 4;
#pragma unroll
    for (int i = 0; i < 2; ++i)
#pragma unroll
        for (int r = 0; r < 4; ++r) {
            int grow = row0 + wm + i * 16 + qr + r;
            if (grow >= M) continue;
#pragma unroll
            for (int j = 0; j < 4; ++j) {
                int gcol = col0 + wn + j * 16 + fr;
                size_t idx = (size_t)grow * 256 + gcol;
                float v = acc[i][j][r] * b2f(gate[(size_t)grow * ldg + goff + gcol]) + b2f(h2[idx]);
                if (eae) v += b2f(eae[idx]);
                out[idx] = v;
            }
        }
}

// ---------------- weight transpose-convert ----------------------------------------------
__global__ __launch_bounds__(256) void k_wconv(
    const float* __restrict__ W, u16* __restrict__ Wt, int K, int N)
{
    int i = blockIdx.x * 256 + threadIdx.x;
    if (i >= K * N) return;
    int n = i / K, k = i - n * K;
    Wt[i] = f2b(W[(size_t)k * N + n]);
}

// ---------------- LN + modulate (bf16 shift/scale) -> bf16, fp32 input ------------------
__global__ __launch_bounds__(256) void k_ln_mod_b16(
    const float* __restrict__ X, u16* __restrict__ Y, int M,
    const u16* __restrict__ ssb, int ldss, int shoff, int scoff)
{
    int row = (blockIdx.x << 2) + (threadIdx.x >> 6);
    if (row >= M) return;
    int lane = threadIdx.x & 63;
    const float* xr = X + (size_t)row * HID + lane * 4;
    float x0 = xr[0], x1 = xr[1], x2 = xr[2], x3 = xr[3];
    float s = x0 + x1 + x2 + x3;
    float q = x0 * x0 + x1 * x1 + x2 * x2 + x3 * x3;
#pragma unroll
    for (int o = 32; o; o >>= 1) { s += __shfl_xor(s, o, 64); q += __shfl_xor(q, o, 64); }
    float m = s * (1.f / HID);
    float r = rsqrtf(q * (1.f / HID) - m * m + 1e-6f);
    const u16* sp = ssb + (size_t)row * ldss;
    ushort4 sh = *(const ushort4*)(sp + shoff + lane * 4);
    ushort4 sc = *(const ushort4*)(sp + scoff + lane * 4);
    ushort4 o;
    o.x = f2b((x0 - m) * r * (1.f + b2f(sc.x)) + b2f(sh.x));
    o.y = f2b((x1 - m) * r * (1.f + b2f(sc.y)) + b2f(sh.y));
    o.z = f2b((x2 - m) * r * (1.f + b2f(sc.z)) + b2f(sh.z));
    o.w = f2b((x3 - m) * r * (1.f + b2f(sc.w)) + b2f(sh.w));
    ((ushort4*)(Y + (size_t)row * HID))[lane] = o;
}

// ---------------- LN + modulate, bf16 input variant -------------------------------------
__global__ __launch_bounds__(256) void k_ln_mod_b16src(
    const u16* __restrict__ X, u16* __restrict__ Y, int M,
    const u16* __restrict__ ssb, int ldss, int shoff, int scoff)
{
    int row = (blockIdx.x << 2) + (threadIdx.x >> 6);
    if (row >= M) return;
    int lane = threadIdx.x & 63;
    ushort4 xv = ((const ushort4*)(X + (size_t)row * HID))[lane];
    float x0 = b2f(xv.x), x1 = b2f(xv.y), x2 = b2f(xv.z), x3 = b2f(xv.w);
    float s = x0 + x1 + x2 + x3;
    float q = x0 * x0 + x1 * x1 + x2 * x2 + x3 * x3;
#pragma unroll
    for (int o = 32; o; o >>= 1) { s += __shfl_xor(s, o, 64); q += __shfl_xor(q, o, 64); }
    float m = s * (1.f / HID);
    float r = rsqrtf(q * (1.f / HID) - m * m + 1e-6f);
    const u16* sp = ssb + (size_t)row * ldss;
    ushort4 sh = *(const ushort4*)(sp + shoff + lane * 4);
    ushort4 sc = *(const ushort4*)(sp + scoff + lane * 4);
    ushort4 o;
    o.x = f2b((x0 - m) * r * (1.f + b2f(sc.x)) + b2f(sh.x));
    o.y = f2b((x1 - m) * r * (1.f + b2f(sc.y)) + b2f(sh.y));
    o.z = f2b((x2 - m) * r * (1.f + b2f(sc.z)) + b2f(sh.z));
    o.w = f2b((x3 - m) * r * (1.f + b2f(sc.w)) + b2f(sh.w));
    ((ushort4*)(Y + (size_t)row * HID))[lane] = o;
}

// ----- Y(bf16) = modulate( ln(A + gate.*Bv) [*g + b], shift, scale ); fp32 Bv -----------
__global__ __launch_bounds__(256) void k_ln_mod_resid_b16(
    const float* __restrict__ A, const float* __restrict__ Bv, u16* __restrict__ Y, int M,
    const u16* __restrict__ gb, int ldg, int goff,
    const u16* __restrict__ ssb, int ldss, int shoff, int scoff,
    const float* __restrict__ gw, const float* __restrict__ bw)
{
    int row = (blockIdx.x << 2) + (threadIdx.x >> 6);
    if (row >= M) return;
    int lane = threadIdx.x & 63;
    const float* ar = A + (size_t)row * HID + lane * 4;
    const float* br = Bv + (size_t)row * HID + lane * 4;
    ushort4 gp = *(const ushort4*)(gb + (size_t)row * ldg + goff + lane * 4);
    float t0 = ar[0] + b2f(gp.x) * br[0];
    float t1 = ar[1] + b2f(gp.y) * br[1];
    float t2 = ar[2] + b2f(gp.z) * br[2];
    float t3 = ar[3] + b2f(gp.w) * br[3];
    float s = t0 + t1 + t2 + t3;
    float q = t0 * t0 + t1 * t1 + t2 * t2 + t3 * t3;
#pragma unroll
    for (int o = 32; o; o >>= 1) { s += __shfl_xor(s, o, 64); q += __shfl_xor(q, o, 64); }
    float m = s * (1.f / HID);
    float r = rsqrtf(q * (1.f / HID) - m * m + 1e-6f);
    float n0 = (t0 - m) * r, n1 = (t1 - m) * r, n2 = (t2 - m) * r, n3 = (t3 - m) * r;
    if (gw) {
        const float* g4 = gw + lane * 4;
        const float* b4 = bw + lane * 4;
        n0 = n0 * g4[0] + b4[0]; n1 = n1 * g4[1] + b4[1];
        n2 = n2 * g4[2] + b4[2]; n3 = n3 * g4[3] + b4[3];
    }
    const u16* sp = ssb + (size_t)row * ldss;
    ushort4 sh = *(const ushort4*)(sp + shoff + lane * 4);
    ushort4 sc = *(const ushort4*)(sp + scoff + lane * 4);
    ushort4 o;
    o.x = f2b(n0 * (1.f + b2f(sc.x)) + b2f(sh.x));
    o.y = f2b(n1 * (1.f + b2f(sc.y)) + b2f(sh.y));
    o.z = f2b(n2 * (1.f + b2f(sc.z)) + b2f(sh.z));
    o.w = f2b(n3 * (1.f + b2f(sc.w)) + b2f(sh.w));
    ((ushort4*)(Y + (size_t)row * HID))[lane] = o;
}

// ----- same, but Bv is bf16 --------------------------------------------------------------
__global__ __launch_bounds__(256) void k_ln_mod_resid_b16bv(
    const float* __restrict__ A, const u16* __restrict__ Bv, u16* __restrict__ Y, int M,
    const u16* __restrict__ gb, int ldg, int goff,
    const u16* __restrict__ ssb, int ldss, int shoff, int scoff)
{
    int row = (blockIdx.x << 2) + (threadIdx.x >> 6);
    if (row >= M) return;
    int lane = threadIdx.x & 63;
    const float* ar = A + (size_t)row * HID + lane * 4;
    ushort4 bv = ((const ushort4*)(Bv + (size_t)row * HID))[lane];
    ushort4 gp = *(const ushort4*)(gb + (size_t)row * ldg + goff + lane * 4);
    float t0 = ar[0] + b2f(gp.x) * b2f(bv.x);
    float t1 = ar[1] + b2f(gp.y) * b2f(bv.y);
    float t2 = ar[2] + b2f(gp.z) * b2f(bv.z);
    float t3 = ar[3] + b2f(gp.w) * b2f(bv.w);
    float s = t0 + t1 + t2 + t3;
    float q = t0 * t0 + t1 * t1 + t2 * t2 + t3 * t3;
#pragma unroll
    for (int o = 32; o; o >>= 1) { s += __shfl_xor(s, o, 64); q += __shfl_xor(q, o, 64); }
    float m = s * (1.f / HID);
    float r = rsqrtf(q * (1.f / HID) - m * m + 1e-6f);
    float n0 = (t0 - m) * r, n1 = (t1 - m) * r, n2 = (t2 - m) * r, n3 = (t3 - m) * r;
    const u16* sp = ssb + (size_t)row * ldss;
    ushort4 sh = *(const ushort4*)(sp + shoff + lane * 4);
    ushort4 sc = *(const ushort4*)(sp + scoff + lane * 4);
    ushort4 o;
    o.x = f2b(n0 * (1.f + b2f(sc.x)) + b2f(sh.x));
    o.y = f2b(n1 * (1.f + b2f(sc.y)) + b2f(sh.y));
    o.z = f2b(n2 * (1.f + b2f(sc.z)) + b2f(sh.z));
    o.w = f2b(n3 * (1.f + b2f(sc.w)) + b2f(sh.w));
    ((ushort4*)(Y + (size_t)row * HID))[lane] = o;
}

// ---------------- CSR build ------------------------------------------------------------
__global__ __launch_bounds__(256) void k_hist(
    const int* __restrict__ tgt, int* __restrict__ counts, int E)
{
    int i = blockIdx.x * 256 + threadIdx.x;
    if (i < E) atomicAdd(&counts[tgt[i]], 1);
}

__global__ __launch_bounds__(256) void k_scan(
    const int* __restrict__ counts, int* __restrict__ offsets, int Nn)
{
    __shared__ int part[256];
    __shared__ int pref[257];
    int t = threadIdx.x;
    int chunk = (Nn + 255) / 256;
    int lo = t * chunk, hi = imin(lo + chunk, Nn);
    int s = 0;
    for (int i = lo; i < hi; ++i) s += counts[i];
    part[t] = s;
    __syncthreads();
    if (t == 0) {
        int run = 0;
        for (int i = 0; i < 256; ++i) { pref[i] = run; run += part[i]; }
        pref[256] = run;
        offsets[Nn] = run;
    }
    __syncthreads();
    int run = pref[t];
    for (int i = lo; i < hi; ++i) { offsets[i] = run; run += counts[i]; }
}

__global__ __launch_bounds__(256) void k_scatter(
    const int* __restrict__ tgt, int* __restrict__ cursor,
    int* __restrict__ eidlist, int E)
{
    int i = blockIdx.x * 256 + threadIdx.x;
    if (i < E) {
        int pos = atomicAdd(&cursor[tgt[i]], 1);
        eidlist[pos] = i;
    }
}

__global__ __launch_bounds__(256) void k_amax_den(
    const float* __restrict__ alpha, const int* __restrict__ offsets,
    const int* __restrict__ eidlist, float* __restrict__ amaxF,
    float* __restrict__ invden, int NH8)
{
    int i = blockIdx.x * 256 + threadIdx.x;
    if (i >= NH8) return;
    int n = i >> 3, h = i & 7;
    int b = offsets[n], e = offsets[n + 1];
    float m = -1e30f;
    for (int k = b; k < e; ++k) m = fmaxf(m, alpha[(size_t)eidlist[k] * 8 + h]);
    float s = 0.f;
    for (int k = b; k < e; ++k) s += __expf(alpha[(size_t)eidlist[k] * 8 + h] - m);
    amaxF[i] = m;
    invden[i] = (s > 0.f) ? 1.f / s : 0.f;
}

__global__ __launch_bounds__(256) void k_norm(
    float* __restrict__ alpha, const float* __restrict__ amaxF,
    const float* __restrict__ invden, const int* __restrict__ tgt, int EH)
{
    int i = blockIdx.x * 256 + threadIdx.x;
    if (i >= EH) return;
    int e = i >> 3, h = i & 7;
    int g = tgt[e];
    alpha[i] = __expf(alpha[i] - amaxF[(size_t)g * 8 + h]) * invden[(size_t)g * 8 + h];
}

// message pass via CSR: hat[n,c] = V[n,c] * sum_{e in CSR[n]} e1[e,c]*w[e,h]
__global__ __launch_bounds__(256) void attn_msg_csr(
    const u16* __restrict__ qkv, const u16* __restrict__ e1b,
    const float* __restrict__ alpha, const int* __restrict__ offsets,
    const int* __restrict__ eidlist, float* __restrict__ hattn)
{
    int n = blockIdx.x;
    int c = threadIdx.x;
    int h = c >> 5;
    int b = offsets[n], e = offsets[n + 1];
    float acc = 0.f;
    for (int k = b; k < e; ++k) {
        int eid = eidlist[k];
        float w = alpha[(size_t)eid * 8 + h];
        acc += b2f(e1b[(size_t)eid * 256 + c]) * w;
    }
    hattn[(size_t)n * 256 + c] = b2f(qkv[(size_t)n * 768 + 512 + c]) * acc;
}

// ---------------------------------------------------------------------------------------
static inline void gemm(hipStream_t st, const u16* A, int lda, const u16* Bt, int ldb,
                        void* C, int ldc, int M, int N, int K,
                        const float* bias, int act, int obf16)
{
    dim3 g(N / 128, (M + 63) / 64);
    hipLaunchKernelGGL(gemm_mfma, g, dim3(256), 0, st, A, lda, Bt, ldb, C, ldc, M, N, K,
                       bias, act, obf16);
}

extern "C" void kernel_launch(void* const* d_in, const int* in_sizes, int n_in,
                              void* d_out, int out_size, void* d_ws, size_t ws_size,
                              hipStream_t stream)
{
    const int Nn = in_sizes[0];
    const int E = in_sizes[3] / HID;

    const float* x        = (const float*)d_in[1];
    const float* t_emb_h  = (const float*)d_in[2];
    const float* edge_attr= (const float*)d_in[3];
    const int*   eidx     = (const int*)d_in[4];
    const float* t_emb_e  = (const float*)d_in[5];
    const float* dist     = (const float*)d_in[6];
    const float* W_ee     = (const float*)d_in[7];
    const float* b_ee     = (const float*)d_in[8];
    const float* W_ad     = (const float*)d_in[9];
    const float* b_ad     = (const float*)d_in[10];
    const float* W_ade    = (const float*)d_in[11];
    const float* b_ade    = (const float*)d_in[12];
    const float* W_qkv    = (const float*)d_in[13];
    const float* W_e0     = (const float*)d_in[14];
    const float* W_e1     = (const float*)d_in[15];
    const float* W_n2e    = (const float*)d_in[16];
    const float* b_n2e    = (const float*)d_in[17];
    const float* g_ln     = (const float*)d_in[18];
    const float* b_ln     = (const float*)d_in[19];
    const float* W_f12    = (const float*)d_in[20];
    const float* W_fout   = (const float*)d_in[21];
    const float* W_fe12   = (const float*)d_in[22];
    const float* W_feout  = (const float*)d_in[23];

    const int* src = eidx;
    const int* tgt = eidx + E;

    float* outN = (float*)d_out;
    float* outE = (float*)d_out + (size_t)Nn * 256;

    // ---- persistent workspace ----
    char* W = (char*)d_ws;
    size_t off = 0;
    auto alloc = [&](size_t bytes) -> size_t {
        size_t o = off; off += (bytes + 255) & ~(size_t)255; return o;
    };
    float*    alpha = (float*)(W + alloc((size_t)E * 8 * 4));
    float*    amaxF = (float*)(W + alloc((size_t)Nn * 8 * 4));
    float*    invden= (float*)(W + alloc((size_t)Nn * 8 * 4));
    float*    hat   = (float*)(W + alloc((size_t)Nn * 256 * 4));
    int*      offs  = (int*)(W + alloc((size_t)(Nn + 1) * 4));
    int*      cursor= (int*)(W + alloc((size_t)Nn * 4));
    int*      eidl  = (int*)(W + alloc((size_t)E * 4));
    u16*      qkvb  = (u16*)(W + alloc((size_t)Nn * 768 * 2));
    u16*      eaeb  = (u16*)(W + alloc((size_t)E * 256 * 2));    // edge_attr_e (bf16)
    u16*      e1b   = (u16*)(W + alloc((size_t)E * 256 * 2));    // e_mod @ W_e1
    u16*      adnb  = (u16*)(W + alloc((size_t)Nn * 1536 * 2));
    u16*      xmb   = (u16*)(W + alloc((size_t)Nn * 256 * 2));
    u16*      h2nb  = (u16*)(W + alloc((size_t)Nn * 256 * 2));
    u16*      cnb   = (u16*)(W + alloc((size_t)Nn * 1024 * 2));
    // bf16 transposed weights (N x K)
    u16* weet   = (u16*)(W + alloc((size_t)256 * 384 * 2));
    u16* wadt   = (u16*)(W + alloc((size_t)1536 * 256 * 2));
    u16* wadet  = (u16*)(W + alloc((size_t)1536 * 256 * 2));
    u16* wqkvt  = (u16*)(W + alloc((size_t)768 * 256 * 2));
    u16* we01t  = (u16*)(W + alloc((size_t)512 * 256 * 2));
    u16* wn2et  = (u16*)(W + alloc((size_t)256 * 256 * 2));
    u16* wf12t  = (u16*)(W + alloc((size_t)2048 * 256 * 2));
    u16* wfoutt = (u16*)(W + alloc((size_t)256 * 1024 * 2));
    u16* wfe12t = (u16*)(W + alloc((size_t)2048 * 256 * 2));
    u16* wfeoutt= (u16*)(W + alloc((size_t)256 * 1024 * 2));

    char* pool = W + off;
    size_t poolB = (ws_size > off) ? (ws_size - off) : 0;
    auto chunkRowsB = [&](size_t bytesPerRow, int total) -> int {
        long c = (long)(poolB / bytesPerRow);
        c = (c / 256) * 256;
        if (c < 256) c = 256;
        if (c > total) c = (long)total;
        return (int)c;
    };

    // ---- CSR build by tgt ----
    hipMemsetAsync(cursor, 0, (size_t)Nn * 4, stream);
    hipLaunchKernelGGL(k_hist, dim3((E + 255) / 256), dim3(256), 0, stream, tgt, cursor, E);
    hipLaunchKernelGGL(k_scan, dim3(1), dim3(256), 0, stream, cursor, offs, Nn);
    hipMemcpyAsync(cursor, offs, (size_t)Nn * 4, hipMemcpyDeviceToDevice, stream);
    hipLaunchKernelGGL(k_scatter, dim3((E + 255) / 256), dim3(256), 0, stream,
                       tgt, cursor, eidl, E);

    // ---- weight conversion ----
    {
        struct WC { const float* w; u16* wt; int K, N; } wl[] = {
            { W_ee,    weet,   384, 256 },
            { W_ad,    wadt,   256, 1536 },
            { W_ade,   wadet,  256, 1536 },
            { W_qkv,   wqkvt,  256, 768 },
            { W_e0,    we01t,  256, 256 },
            { W_e1,    we01t + 256 * 256, 256, 256 },
            { W_n2e,   wn2et,  256, 256 },
            { W_f12,   wf12t,  256, 2048 },
            { W_fout,  wfoutt, 1024, 256 },
            { W_fe12,  wfe12t, 256, 2048 },
            { W_feout, wfeoutt,1024, 256 },
        };
        for (auto& e : wl) {
            int cnt = e.K * e.N;
            hipLaunchKernelGGL(k_wconv, dim3((cnt + 255) / 256), dim3(256), 0, stream,
                               e.w, e.wt, e.K, e.N);
        }
    }

    // ---- phase 1: node pre (silu fused into adaln GEMM A-staging) ----
    hipLaunchKernelGGL(gemm_siluA, dim3(12, (Nn + 63) / 64), dim3(256), 0, stream,
                       t_emb_h, wadt, adnb, 1536, Nn, b_ad);
    hipLaunchKernelGGL(k_ln_mod_b16, dim3((Nn + 3) / 4), dim3(256), 0, stream,
                       x, xmb, Nn, adnb, 1536, 0, 256);
    gemm(stream, xmb, 256, wqkvt, 256, qkvb, 768, Nn, 768, 256, nullptr, 0, 1);

    // ---- phase 2: edge pre ----
    {
        int C = chunkRowsB(1024 + 512, E);
        char* p = pool;
        u16* emsb = (u16*)p; p += (size_t)C * 1024;   // adaln_e[:,0:512) (bf16)
        u16* emod = (u16*)p;                          // C x 256 bf16
        for (int s = 0; s < E; s += C) {
            int cc = (E - s < C) ? (E - s) : C;
            hipLaunchKernelGGL(gemm_cat, dim3(2, (cc + 63) / 64), dim3(256), 0, stream,
                               edge_attr + (size_t)s * 256, dist + (size_t)s * 128,
                               weet, eaeb + (size_t)s * 256, cc, b_ee);
            hipLaunchKernelGGL(gemm_siluA, dim3(4, (cc + 63) / 64), dim3(256), 0, stream,
                               t_emb_e + (size_t)s * 256, wadet, emsb, 512, cc, b_ade);
            hipLaunchKernelGGL(k_ln_mod_b16src, dim3((cc + 3) / 4), dim3(256), 0, stream,
                               eaeb + (size_t)s * 256, emod, cc, emsb, 512, 0, 256);
            hipLaunchKernelGGL(gemm_e01, dim3(4, (cc + 63) / 64), dim3(256), 0, stream,
                               emod, we01t, e1b + (size_t)s * 256, cc,
                               qkvb, src + s, tgt + s, alpha + (size_t)s * 8);
        }
    }

    // ---- phase 3: softmax stats + normalize ----
    hipLaunchKernelGGL(k_amax_den, dim3((Nn * 8 + 255) / 256), dim3(256), 0, stream,
                       alpha, offs, eidl, amaxF, invden, Nn * 8);
    hipLaunchKernelGGL(k_norm, dim3((E * 8 + 255) / 256), dim3(256), 0, stream,
                       alpha, amaxF, invden, tgt, E * 8);

    // ---- phase 4: message pass via CSR ----
    hipLaunchKernelGGL(attn_msg_csr, dim3(Nn), dim3(256), 0, stream,
                       qkvb, e1b, alpha, offs, eidl, hat);

    // ---- phase 5: node finish ----
    hipLaunchKernelGGL(k_ln_mod_resid_b16, dim3((Nn + 3) / 4), dim3(256), 0, stream,
                       x, hat, h2nb, Nn, adnb, 1536, 512, adnb, 1536, 768, 1024, g_ln, b_ln);
    hipLaunchKernelGGL(gemm_ffn12, dim3(16, (Nn + 63) / 64), dim3(256), 0, stream,
                       h2nb, wf12t, cnb, Nn);
    hipLaunchKernelGGL(gemm_out_final, dim3(2, (Nn + 63) / 64), dim3(256), 0, stream,
                       cnb, wfoutt, (const u16*)nullptr, h2nb, adnb, 1536, 1280, outN, Nn);

    // ---- phase 6: edge finish ----
    {
        int C = chunkRowsB(2048 + 512 + 512 + 2048, E);
        char* p = pool;
        u16*   em2b = (u16*)p;  p += (size_t)C * 2048;   // adaln_e[:,512:1536)
        u16*   hep  = (u16*)p;  p += (size_t)C * 512;    // bf16
        u16*   h2e  = (u16*)p;  p += (size_t)C * 512;
        u16*   cne  = (u16*)p;                            // swiglu out C x 1024
        for (int s = 0; s < E; s += C) {
            int cc = (E - s < C) ? (E - s) : C;
            hipLaunchKernelGGL(gemm_gsum, dim3(2, (cc + 63) / 64), dim3(256), 0, stream,
                               hat, src + s, tgt + s, wn2et, hep, cc, b_n2e);
            hipLaunchKernelGGL(gemm_siluA, dim3(8, (cc + 63) / 64), dim3(256), 0, stream,
                               t_emb_e + (size_t)s * 256, wadet + 512 * 256, em2b, 1024,
                               cc, b_ade + 512);
            hipLaunchKernelGGL(k_ln_mod_resid_b16bv, dim3((cc + 3) / 4), dim3(256), 0, stream,
                               edge_attr + (size_t)s * 256, hep, h2e, cc,
                               em2b, 1024, 0, em2b, 1024, 256, 512);
            hipLaunchKernelGGL(gemm_ffn12, dim3(16, (cc + 63) / 64), dim3(256), 0, stream,
                               h2e, wfe12t, cne, cc);
            hipLaunchKernelGGL(gemm_out_final, dim3(2, (cc + 63) / 64), dim3(256), 0, stream,
                               cne, wfeoutt, eaeb + (size_t)s * 256, h2e,
                               em2b, 1024, 768, outE + (size_t)s * 256, cc);
        }
    }
    (void)n_in; (void)out_size;
}